// Round 12
// baseline (340.988 us; speedup 1.0000x reference)
//
#include <hip/hip_runtime.h>

#define B_    8
#define C_    256
#define R_    14
#define R2    196
#define N3    2744     // 14^3
#define NP    2752     // padded (43*64): guard-free tile staging
#define NH    4
#define KD    16
#define DV    64
#define QKVO  96       // 2*KD + DV
#define MT    64       // m-tile in attention
#define NTILE 43
#define SPLIT 4
#define TPC   11       // tiles per m-chunk

#define SC2   0.36067376f   // 0.25 * log2(e)
#define LOG2E 1.44269504f
#define ABSZ  406           // 196 real + sentinel region (idx in [210,405] w/ mx=my=27)

typedef __attribute__((ext_vector_type(8))) short short8v;
typedef __attribute__((ext_vector_type(4))) short short4v;
typedef __attribute__((ext_vector_type(4))) float float4v;

__device__ __forceinline__ int iabs(int v){ return v < 0 ? -v : v; }

// fp32 -> bf16 round-to-nearest-even (finite inputs)
__device__ __forceinline__ short f2bf(float f){
    union { float f; unsigned int u; } c; c.f = f;
    return (short)((c.u + 0x7FFFu + ((c.u >> 16) & 1u)) >> 16);
}
__device__ __forceinline__ float bf2f(short s){
    union { unsigned int u; float f; } c; c.u = ((unsigned int)(unsigned short)s) << 16;
    return c.f;
}

// ---------------------------------------------------------------------------
// wprep: Wp -> bf16 hi/lo split; Wqkv*qkv_scale -> bf16 hi/lo split.
// grid 256, block 256 (i < 65536)
// ---------------------------------------------------------------------------
__global__ __launch_bounds__(256)
void wprep_kernel(const float* __restrict__ Wp, short* __restrict__ whi,
                  short* __restrict__ wlo, const float* __restrict__ Wqkv,
                  const float* __restrict__ qsc, short* __restrict__ wqhi,
                  short* __restrict__ wqlo)
{
    int i = blockIdx.x * 256 + threadIdx.x;   // 65536 total
    {
        float w = Wp[i];
        short hi = f2bf(w);
        short lo = f2bf(w - bf2f(hi));
        whi[i] = hi; wlo[i] = lo;
    }
    if (i < NH * QKVO * 64) {                 // 24576
        int o_all = i >> 6;                   // head*96 + o
        float w = Wqkv[i] * qsc[o_all];       // fold scale into W rows
        short hi = f2bf(w);
        short lo = f2bf(w - bf2f(hi));
        wqhi[i] = hi; wqlo[i] = lo;
    }
}

// ---------------------------------------------------------------------------
// QKV: split-bf16 MFMA GEMM + fused combine of PREVIOUS head's partials.
// For head>0: h_{head-1} = (sum_z pacc)*(1/sum_z pl) computed inline (same fp32
// math/order as the combine kernel), written to h and added to feat.
// grid (43, B), block 256
// ---------------------------------------------------------------------------
__global__ __launch_bounds__(256, 2)
void qkv_mfma(const float* __restrict__ x, float* __restrict__ h,
              const float* __restrict__ pacc, const float* __restrict__ pl,
              const short* __restrict__ wqhi, const short* __restrict__ wqlo,
              const float* __restrict__ qbi,
              float* __restrict__ q0, short* __restrict__ kbf, short* __restrict__ vbf,
              int head)
{
    __shared__ short fhi[64][72];   // [n][c] feat hi
    __shared__ short flo[64][72];   // [n][c] feat lo
    __shared__ float bsh[96];
    __shared__ float linv_s[64];

    const int b = blockIdx.y;
    const int n0 = blockIdx.x * 64;
    const int t = threadIdx.x;
    const int w = t >> 6, l = t & 63, g = l >> 4, ln = l & 15;

    if (t < 96) bsh[t] = qbi[head * QKVO + t];

    if (head > 0) {               // stage 1/sum(l) for this n-tile
        if (t < 64) {
            int n = n0 + t;
            float lt = pl[(size_t)(b * SPLIT + 0) * NP + n]
                     + pl[(size_t)(b * SPLIT + 1) * NP + n]
                     + pl[(size_t)(b * SPLIT + 2) * NP + n]
                     + pl[(size_t)(b * SPLIT + 3) * NP + n];
            linv_s[t] = 1.f / lt;  // garbage for pad n (unused)
        }
        __syncthreads();
    }

    // ---- stage feat transposed, hi/lo split: thread = (c = t&63, n-group) ----
    {
        const int sc_ = t & 63;
        const int sng = (t >> 6) * 16;        // n local base
        const int nb = n0 + sng;
        const float* xs = x + ((size_t)b * C_ + head * DV + sc_) * N3 + nb;
        float fv[16];
        const bool fullblk = (nb + 15 < N3);
        if (fullblk) {
#pragma unroll
            for (int e4 = 0; e4 < 4; e4++) {
                float4 xv = ((const float4*)xs)[e4];
                fv[4*e4+0] = xv.x; fv[4*e4+1] = xv.y; fv[4*e4+2] = xv.z; fv[4*e4+3] = xv.w;
            }
        } else {
#pragma unroll
            for (int e = 0; e < 16; e++) fv[e] = (nb + e < N3) ? xs[e] : 0.f;
        }
        if (head > 0) {
            const float* pb = pacc + (size_t)b * SPLIT * DV * NP + (size_t)sc_ * NP + nb;
            float* hw = h + ((size_t)b * C_ + (head - 1) * DV + sc_) * N3 + nb;
            const size_t zs = (size_t)DV * NP;
            if (fullblk) {
#pragma unroll
                for (int e4 = 0; e4 < 4; e4++) {
                    float4 a0 = ((const float4*)(pb         ))[e4];
                    float4 a1 = ((const float4*)(pb +     zs))[e4];
                    float4 a2 = ((const float4*)(pb + 2 * zs))[e4];
                    float4 a3 = ((const float4*)(pb + 3 * zs))[e4];
                    float hc[4];
                    hc[0] = (a0.x + a1.x + a2.x + a3.x) * linv_s[sng + 4*e4 + 0];
                    hc[1] = (a0.y + a1.y + a2.y + a3.y) * linv_s[sng + 4*e4 + 1];
                    hc[2] = (a0.z + a1.z + a2.z + a3.z) * linv_s[sng + 4*e4 + 2];
                    hc[3] = (a0.w + a1.w + a2.w + a3.w) * linv_s[sng + 4*e4 + 3];
                    *(float4*)&hw[4*e4] = make_float4(hc[0], hc[1], hc[2], hc[3]);
                    fv[4*e4+0] += hc[0]; fv[4*e4+1] += hc[1];
                    fv[4*e4+2] += hc[2]; fv[4*e4+3] += hc[3];
                }
            } else {
#pragma unroll
                for (int e = 0; e < 16; e++) {
                    if (nb + e < N3) {
                        float a = pb[e] + pb[e + zs] + pb[e + 2*zs] + pb[e + 3*zs];
                        float hc = a * linv_s[sng + e];
                        hw[e] = hc;
                        fv[e] += hc;
                    }
                }
            }
        }
#pragma unroll
        for (int e = 0; e < 16; e++) {
            short hi = f2bf(fv[e]);
            short lo = f2bf(fv[e] - bf2f(hi));
            fhi[sng + e][sc_] = hi;
            flo[sng + e][sc_] = lo;
        }
    }
    __syncthreads();

    // ---- GEMM: 6 o-subtiles x this wave's n-subtile, K=64 ----
    float4v acc[6];
#pragma unroll
    for (int os = 0; os < 6; os++) acc[os] = (float4v){0.f, 0.f, 0.f, 0.f};

    const short* wqh = wqhi + head * QKVO * 64;
    const short* wql = wqlo + head * QKVO * 64;
#pragma unroll
    for (int ck = 0; ck < 2; ck++) {
        short8v bh = *(const short8v*)&fhi[w * 16 + ln][ck * 32 + g * 8];
        short8v bl = *(const short8v*)&flo[w * 16 + ln][ck * 32 + g * 8];
#pragma unroll
        for (int os = 0; os < 6; os++) {
            size_t off = (size_t)(os * 16 + ln) * 64 + ck * 32 + g * 8;
            short8v wh = *(const short8v*)(wqh + off);
            short8v wl = *(const short8v*)(wql + off);
            acc[os] = __builtin_amdgcn_mfma_f32_16x16x32_bf16(wh, bh, acc[os], 0, 0, 0);
            acc[os] = __builtin_amdgcn_mfma_f32_16x16x32_bf16(wh, bl, acc[os], 0, 0, 0);
            acc[os] = __builtin_amdgcn_mfma_f32_16x16x32_bf16(wl, bh, acc[os], 0, 0, 0);
        }
    }

    // ---- epilogue: D[o = os*16+g*4+r][n = n0+w*16+ln] ----
    const int n_ = n0 + w * 16 + ln;          // < NP always
    const bool ok = n_ < N3;
    float* qo = q0 + (size_t)b * KD * NP;
    short* ko = kbf + (size_t)b * NP * 16 + (size_t)n_ * 16;
    short* vo = vbf + (size_t)b * DV * NP;
#pragma unroll
    for (int os = 0; os < 6; os++) {
#pragma unroll
        for (int r = 0; r < 4; r++) {
            int o = os * 16 + g * 4 + r;
            float y = ok ? acc[os][r] + bsh[o] : 0.f;
            if (o < KD)            qo[(size_t)o * NP + n_] = y;
            else if (o < 2 * KD)   ko[o - KD] = f2bf(y);
            else                   vo[(size_t)(o - 2 * KD) * NP + n_] = f2bf(y);
        }
    }
}

// ---------------------------------------------------------------------------
// Depthwise 5x5x5 SAME conv: zero-padded 18^3 LDS volume, branchless.
// grid (KD, B), block 256
// ---------------------------------------------------------------------------
__global__ __launch_bounds__(256)
void dwconv_kernel(float* __restrict__ q0, const float* __restrict__ Wdw,
                   const float* __restrict__ dsc, const float* __restrict__ dbi,
                   int head)
{
    __shared__ float pv[18 * 18 * 18];
    int b = blockIdx.y, c = blockIdx.x;
    int t = threadIdx.x;
    float* qc = q0 + ((size_t)b * KD + c) * NP;

    for (int i = t; i < 5832; i += 256) pv[i] = 0.f;
    __syncthreads();
    for (int i = t; i < N3; i += 256) {
        int xx = i / R2; int rem = i - xx * R2; int yy = rem / R_; int zz = rem - yy * R_;
        pv[(xx + 2) * 324 + (yy + 2) * 18 + (zz + 2)] = qc[i];
    }
    __syncthreads();

    const float* w = Wdw + (head * KD + c) * 125;
    float scl = dsc[head * KD + c], bia = dbi[head * KD + c];

    if (t < R2) {
        int x = t / R_, y = t - (t / R_) * R_;
        float acc[14];
#pragma unroll
        for (int z = 0; z < 14; z++) acc[z] = 0.f;
#pragma unroll
        for (int a = 0; a < 5; a++) {
#pragma unroll
            for (int bb = 0; bb < 5; bb++) {
                const float* base = &pv[(x + a) * 324 + (y + bb) * 18];
                float col[18];
#pragma unroll
                for (int j = 0; j < 18; j++) col[j] = base[j];
#pragma unroll
                for (int cc = 0; cc < 5; cc++) {
                    float wv = w[a * 25 + bb * 5 + cc];
#pragma unroll
                    for (int z = 0; z < 14; z++) acc[z] += wv * col[z + cc];
                }
            }
        }
        float* qo = qc + x * R2 + y * R_;
#pragma unroll
        for (int z = 0; z < 14; z++) qo[z] = acc[z] * scl + bia;
    }
}

// ---------------------------------------------------------------------------
// Attention partial (r10-proven softmax/lsum; only change vs r10: clamp-free
// extended ab2 table — provably equivalent values).
// grid (43, B, SPLIT), block 256.
// ---------------------------------------------------------------------------
__global__ __launch_bounds__(256, 4)
void attn_partial(const float* __restrict__ q0, const short* __restrict__ kbf,
                  const short* __restrict__ vbf, float* __restrict__ pacc,
                  float* __restrict__ pl, const float* __restrict__ abias, int head)
{
    __shared__ short ktT[64][40];      // [m][d], d 0..15 real, 16..31 zeros, pad->40
    __shared__ short vtT[64][72];      // [c][m], pad 72
    __shared__ short plds[4][16][72];  // per-wave P [n][m]
    __shared__ int   mxa[64];
    __shared__ float ab2[ABSZ];        // bias*log2e; [196..405] = -20000 sentinel

    const int b = blockIdx.y, z = blockIdx.z;
    const int qbase = blockIdx.x * 64;
    const int t = threadIdx.x;
    const int w = t >> 6;
    const int l = t & 63;
    const int g = l >> 4;
    const int ln = l & 15;

    for (int i = t; i < ABSZ; i += 256)
        ab2[i] = (i < 196) ? abias[head * R2 + i] * LOG2E : -20000.0f;

    const float* qq  = q0  + (size_t)b * KD * NP;
    const short* kbs = kbf + (size_t)b * NP * 16;
    const short* vbs = vbf + (size_t)b * DV * NP;

    // zero-fill ktT d=16..31 (in-loop staging only writes d<16)
    {
        int mm = t & 63, dg = t >> 6;
        short4v zz = {0, 0, 0, 0};
        *(short4v*)&ktT[mm][16 + dg * 4] = zz;
    }

    const int n_my = qbase + w * 16 + ln;
    short8v qf;
#pragma unroll
    for (int j = 0; j < 8; j++) {
        int d = g * 8 + j;
        qf[j] = (d < KD) ? f2bf(qq[(size_t)d * NP + n_my]) : (short)0;
    }
    const int nmc = n_my < N3 ? n_my : 0;
    const int nx = nmc / R2, ny = (nmc - nx * R2) / R_;

    float4v acc[4];
#pragma unroll
    for (int cs = 0; cs < 4; cs++) acc[cs] = (float4v){0.f, 0.f, 0.f, 0.f};
    float lsum = 0.f;

    const int tEnd = min(z * TPC + TPC, NTILE);
    for (int t0 = z * TPC; t0 < tEnd; t0++) {
        const int m0 = t0 * MT;
        __syncthreads();
        {   // stage K: thread (mm=t>>2, kq=t&3): b64 copy (pad rows are zeros)
            int mm = t >> 2, kq = t & 3;
            short4v kv = *(const short4v*)(kbs + (size_t)(m0 + mm) * 16 + kq * 4);
            *(short4v*)&ktT[mm][kq * 4] = kv;
        }
        {   // stage V: thread (c=t>>2, mq=t&3): 32B copy
            int c = t >> 2, mq = t & 3;
            const short* vs = vbs + (size_t)c * NP + m0 + mq * 16;
            short8v s0 = ((const short8v*)vs)[0];
            short8v s1 = ((const short8v*)vs)[1];
            *(short8v*)&vtT[c][mq * 16]     = s0;
            *(short8v*)&vtT[c][mq * 16 + 8] = s1;
        }
        if (t < 64) {
            int m = m0 + t;
            int mx, my;
            if (m < N3) { mx = m / R2; int rem = m - mx * R2; my = rem / R_; }
            else        { mx = 27; my = 27; }   // sentinel: idx in [210,405] -> -20000
            mxa[t] = (mx << 8) | my;
        }
        __syncthreads();

        // ---- QK^T + softmax (guard-free, clamp-free) ----
#pragma unroll
        for (int ms = 0; ms < 4; ms++) {
            short8v af = *(const short8v*)&ktT[ms * 16 + ln][g * 8];
            float4v zf = {0.f, 0.f, 0.f, 0.f};
            float4v s = __builtin_amdgcn_mfma_f32_16x16x32_bf16(af, qf, zf, 0, 0, 0);
            int4 pk4 = *(const int4*)&mxa[ms * 16 + g * 4];
            int pka[4] = {pk4.x, pk4.y, pk4.z, pk4.w};
            float p[4];
#pragma unroll
            for (int r = 0; r < 4; r++) {
                int mx = pka[r] >> 8, my = pka[r] & 255;
                int dx, idx;
                asm("v_sad_u32 %0, %1, %2, 0" : "=v"(dx) : "v"(nx), "v"(mx));
                int t14 = dx * 14;
                asm("v_sad_u32 %0, %1, %2, %3" : "=v"(idx) : "v"(ny), "v"(my), "v"(t14));
                float lg2 = fmaf(s[r], SC2, ab2[idx]);
                p[r] = exp2f(lg2);
                lsum += p[r];
            }
            unsigned pk01, pk23;
            asm("v_cvt_pk_bf16_f32 %0, %1, %2" : "=v"(pk01) : "v"(p[0]), "v"(p[1]));
            asm("v_cvt_pk_bf16_f32 %0, %1, %2" : "=v"(pk23) : "v"(p[2]), "v"(p[3]));
            uint2 pw = make_uint2(pk01, pk23);
            *(uint2*)&plds[w][ln][ms * 16 + g * 4] = pw;
        }

        // ---- PV ----
#pragma unroll
        for (int ck = 0; ck < 2; ck++) {
            short8v pa = *(const short8v*)&plds[w][ln][ck * 32 + g * 8];
#pragma unroll
            for (int cs = 0; cs < 4; cs++) {
                short8v vf = *(const short8v*)&vtT[cs * 16 + ln][ck * 32 + g * 8];
                acc[cs] = __builtin_amdgcn_mfma_f32_16x16x32_bf16(pa, vf, acc[cs], 0, 0, 0);
            }
        }
    }

    // ---- epilogue (r10-proven) ----
    lsum += __shfl_xor(lsum, 16);
    lsum += __shfl_xor(lsum, 32);

    float* pbase = pacc + (size_t)(b * SPLIT + z) * DV * NP;
    if (l < 16) {
        int n_l = qbase + w * 16 + l;
        if (n_l < N3) pl[(size_t)(b * SPLIT + z) * NP + n_l] = lsum;
    }
    const int n0w = qbase + w * 16 + g * 4;
    if (n0w < N3) {
#pragma unroll
        for (int cs = 0; cs < 4; cs++) {
            int c = cs * 16 + ln;
            *(float4v*)&pbase[(size_t)c * NP + n0w] = acc[cs];
        }
    }
}

// ---------------------------------------------------------------------------
// Combine SPLIT partials (only the LAST head; earlier heads are combined
// inside the next head's qkv): h = (sum_z acc_z) / (sum_z l_z)
// grid (11, B, 4 ch-groups), block 256
// ---------------------------------------------------------------------------
__global__ __launch_bounds__(256)
void attn_combine(const float* __restrict__ pacc, const float* __restrict__ pl,
                  float* __restrict__ h, int head)
{
    int b = blockIdx.y;
    int ch0 = blockIdx.z * 16;
    int r = blockIdx.x * 256 + threadIdx.x;
    if (r >= N3) return;
    float l = 0.f;
#pragma unroll
    for (int z = 0; z < SPLIT; z++) l += pl[(size_t)(b * SPLIT + z) * NP + r];
    float inv = 1.f / l;
    float* hb = h + ((size_t)b * C_ + head * DV) * N3 + r;
    const float* pb = pacc + (size_t)b * SPLIT * DV * NP + r;
#pragma unroll
    for (int cc = 0; cc < 16; cc++) {
        int ch = ch0 + cc;
        float a = 0.f;
#pragma unroll
        for (int z = 0; z < SPLIT; z++) a += pb[(size_t)(z * DV + ch) * NP];
        hb[(size_t)ch * N3] = a * inv;
    }
}

// ---------------------------------------------------------------------------
// Projection: split-bf16 MFMA. out = psc*(Wp @ relu(h)) + pbi
// grid (43 n-tiles, B), block 256
// ---------------------------------------------------------------------------
__global__ __launch_bounds__(256, 2)
void proj_kernel(const float* __restrict__ h, const short* __restrict__ whi,
                 const short* __restrict__ wlo, const float* __restrict__ psc,
                 const float* __restrict__ pbi, float* __restrict__ out)
{
    __shared__ short hhi[64][40];
    __shared__ short hlo[64][40];

    const int b = blockIdx.y;
    const int n0 = blockIdx.x * 64;
    const int t = threadIdx.x;
    const int w = t >> 6, l = t & 63, g = l >> 4, ln = l & 15;

    float4v acc[4][4];
#pragma unroll
    for (int os = 0; os < 4; os++)
#pragma unroll
        for (int ns = 0; ns < 4; ns++) acc[os][ns] = (float4v){0.f, 0.f, 0.f, 0.f};

    const float* hb = h + (size_t)b * C_ * N3;
    const int sc = t >> 3;
    const int sn = (t & 7) * 8;

    for (int c0 = 0; c0 < 256; c0 += 32) {
        __syncthreads();
        {
            const float* hsrc = hb + (size_t)(c0 + sc) * N3 + n0 + sn;
            float4 f0 = ((const float4*)hsrc)[0];
            float4 f1 = ((const float4*)hsrc)[1];
            float va[8] = { f0.x, f0.y, f0.z, f0.w, f1.x, f1.y, f1.z, f1.w };
#pragma unroll
            for (int u = 0; u < 8; u++) {
                float v = va[u] > 0.f ? va[u] : 0.f;
                short hi = f2bf(v);
                short lo = f2bf(v - bf2f(hi));
                hhi[sn + u][sc] = hi;
                hlo[sn + u][sc] = lo;
            }
        }
        __syncthreads();

        short8v wh[4], wl[4];
#pragma unroll
        for (int os = 0; os < 4; os++) {
            size_t off = (size_t)(64 * w + os * 16 + ln) * 256 + c0 + g * 8;
            wh[os] = *(const short8v*)(whi + off);
            wl[os] = *(const short8v*)(wlo + off);
        }
#pragma unroll
        for (int ns = 0; ns < 4; ns++) {
            short8v bh = *(const short8v*)&hhi[ns * 16 + ln][g * 8];
            short8v bl = *(const short8v*)&hlo[ns * 16 + ln][g * 8];
#pragma unroll
            for (int os = 0; os < 4; os++) {
                acc[os][ns] = __builtin_amdgcn_mfma_f32_16x16x32_bf16(wh[os], bh, acc[os][ns], 0, 0, 0);
                acc[os][ns] = __builtin_amdgcn_mfma_f32_16x16x32_bf16(wh[os], bl, acc[os][ns], 0, 0, 0);
                acc[os][ns] = __builtin_amdgcn_mfma_f32_16x16x32_bf16(wl[os], bh, acc[os][ns], 0, 0, 0);
            }
        }
    }

    float* ob = out + (size_t)b * C_ * N3;
#pragma unroll
    for (int os = 0; os < 4; os++) {
#pragma unroll
        for (int r = 0; r < 4; r++) {
            int o = 64 * w + os * 16 + g * 4 + r;
            float s0 = psc[o], b0 = pbi[o];
#pragma unroll
            for (int ns = 0; ns < 4; ns++) {
                int n = n0 + ns * 16 + ln;
                if (n < N3) ob[(size_t)o * N3 + n] = acc[os][ns][r] * s0 + b0;
            }
        }
    }
}

// ---------------------------------------------------------------------------
extern "C" void kernel_launch(void* const* d_in, const int* in_sizes, int n_in,
                              void* d_out, int out_size, void* d_ws, size_t ws_size,
                              hipStream_t stream)
{
    const float* x    = (const float*)d_in[0];
    const float* Wqkv = (const float*)d_in[1];
    const float* qsc  = (const float*)d_in[2];
    const float* qbi  = (const float*)d_in[3];
    const float* Wdw  = (const float*)d_in[4];
    const float* dsc  = (const float*)d_in[5];
    const float* dbi  = (const float*)d_in[6];
    const float* Wp   = (const float*)d_in[7];
    const float* psc  = (const float*)d_in[8];
    const float* pbi  = (const float*)d_in[9];
    const float* ab   = (const float*)d_in[10];
    // d_in[11] = bias_idx: unused (computed analytically)

    float* out = (float*)d_out;
    char*  wsb = (char*)d_ws;
    float* q0   = (float*)wsb;                                  // B*KD*NP f32
    short* kbf  = (short*)(q0 + (size_t)B_ * KD * NP);          // B*NP*16 bf16
    short* vbf  = kbf + (size_t)B_ * NP * 16;                   // B*DV*NP bf16
    float* h    = (float*)(vbf + (size_t)B_ * DV * NP);         // B*C*N3 f32
    float* pacc = h + (size_t)B_ * C_ * N3;                     // B*SPLIT*DV*NP f32
    float* pl   = pacc + (size_t)B_ * SPLIT * DV * NP;          // B*SPLIT*NP f32
    short* whi  = (short*)(pl + (size_t)B_ * SPLIT * NP);       // 256*256 bf16
    short* wlo  = whi + 256 * 256;                              // 256*256 bf16
    short* wqhi = wlo + 256 * 256;                              // 4*96*64 bf16
    short* wqlo = wqhi + NH * QKVO * 64;                        // 4*96*64 bf16

    wprep_kernel<<<256, 256, 0, stream>>>(Wp, whi, wlo, Wqkv, qsc, wqhi, wqlo);

    for (int head = 0; head < NH; head++) {
        qkv_mfma<<<dim3(43, B_), 256, 0, stream>>>(x, h, pacc, pl, wqhi, wqlo, qbi,
                                                   q0, kbf, vbf, head);
        dwconv_kernel<<<dim3(KD, B_), 256, 0, stream>>>(q0, Wdw, dsc, dbi, head);
        attn_partial<<<dim3(43, B_, SPLIT), 256, 0, stream>>>(q0, kbf, vbf, pacc, pl, ab, head);
    }
    attn_combine<<<dim3(11, B_, 4), 256, 0, stream>>>(pacc, pl, h, NH - 1);
    proj_kernel<<<dim3(43, B_), 256, 0, stream>>>(h, whi, wlo, psc, pbi, out);
}

// Round 14
// 337.584 us; speedup vs baseline: 1.0101x; 1.0101x over previous
//
#include <hip/hip_runtime.h>

#define B_    8
#define C_    256
#define R_    14
#define R2    196
#define N3    2744     // 14^3
#define NP    2752     // padded (43*64): guard-free tile staging
#define NH    4
#define KD    16
#define DV    64
#define QKVO  96       // 2*KD + DV
#define MT    64       // m-tile in attention
#define NTILE 43
#define SPLIT 4
#define TPC   11       // tiles per m-chunk

#define SC2   0.36067376f   // 0.25 * log2(e)
#define LOG2E 1.44269504f
#define ABSZ  406           // 196 real + sentinel region (idx in [210,405] w/ mx=my=27)

typedef __attribute__((ext_vector_type(8))) short short8v;
typedef __attribute__((ext_vector_type(4))) short short4v;
typedef __attribute__((ext_vector_type(4))) float float4v;

__device__ __forceinline__ int iabs(int v){ return v < 0 ? -v : v; }

// fp32 -> bf16 round-to-nearest-even (finite inputs)
__device__ __forceinline__ short f2bf(float f){
    union { float f; unsigned int u; } c; c.f = f;
    return (short)((c.u + 0x7FFFu + ((c.u >> 16) & 1u)) >> 16);
}
__device__ __forceinline__ float bf2f(short s){
    union { unsigned int u; float f; } c; c.u = ((unsigned int)(unsigned short)s) << 16;
    return c.f;
}

// ---------------------------------------------------------------------------
// wprep: Wp -> bf16 hi/lo split; Wqkv*qkv_scale -> bf16 hi/lo split.
// grid 256, block 256 (i < 65536)
// ---------------------------------------------------------------------------
__global__ __launch_bounds__(256)
void wprep_kernel(const float* __restrict__ Wp, short* __restrict__ whi,
                  short* __restrict__ wlo, const float* __restrict__ Wqkv,
                  const float* __restrict__ qsc, short* __restrict__ wqhi,
                  short* __restrict__ wqlo)
{
    int i = blockIdx.x * 256 + threadIdx.x;   // 65536 total
    {
        float w = Wp[i];
        short hi = f2bf(w);
        short lo = f2bf(w - bf2f(hi));
        whi[i] = hi; wlo[i] = lo;
    }
    if (i < NH * QKVO * 64) {                 // 24576
        int o_all = i >> 6;                   // head*96 + o
        float w = Wqkv[i] * qsc[o_all];       // fold scale into W rows
        short hi = f2bf(w);
        short lo = f2bf(w - bf2f(hi));
        wqhi[i] = hi; wqlo[i] = lo;
    }
}

// ---------------------------------------------------------------------------
// QKV: split-bf16 MFMA GEMM + fused combine of PREVIOUS head's partials.
// grid (43, B), block 256
// ---------------------------------------------------------------------------
__global__ __launch_bounds__(256, 2)
void qkv_mfma(const float* __restrict__ x, float* __restrict__ h,
              const float* __restrict__ pacc, const float* __restrict__ pl,
              const short* __restrict__ wqhi, const short* __restrict__ wqlo,
              const float* __restrict__ qbi,
              float* __restrict__ q0, short* __restrict__ kbf, short* __restrict__ vbf,
              int head)
{
    __shared__ short fhi[64][72];   // [n][c] feat hi
    __shared__ short flo[64][72];   // [n][c] feat lo
    __shared__ float bsh[96];
    __shared__ float linv_s[64];

    const int b = blockIdx.y;
    const int n0 = blockIdx.x * 64;
    const int t = threadIdx.x;
    const int w = t >> 6, l = t & 63, g = l >> 4, ln = l & 15;

    if (t < 96) bsh[t] = qbi[head * QKVO + t];

    if (head > 0) {               // stage 1/sum(l) for this n-tile
        if (t < 64) {
            int n = n0 + t;
            float lt = pl[(size_t)(b * SPLIT + 0) * NP + n]
                     + pl[(size_t)(b * SPLIT + 1) * NP + n]
                     + pl[(size_t)(b * SPLIT + 2) * NP + n]
                     + pl[(size_t)(b * SPLIT + 3) * NP + n];
            linv_s[t] = 1.f / lt;  // garbage for pad n (unused)
        }
        __syncthreads();
    }

    // ---- stage feat transposed, hi/lo split: thread = (c = t&63, n-group) ----
    {
        const int sc_ = t & 63;
        const int sng = (t >> 6) * 16;        // n local base
        const int nb = n0 + sng;
        const float* xs = x + ((size_t)b * C_ + head * DV + sc_) * N3 + nb;
        float fv[16];
        const bool fullblk = (nb + 15 < N3);
        if (fullblk) {
#pragma unroll
            for (int e4 = 0; e4 < 4; e4++) {
                float4 xv = ((const float4*)xs)[e4];
                fv[4*e4+0] = xv.x; fv[4*e4+1] = xv.y; fv[4*e4+2] = xv.z; fv[4*e4+3] = xv.w;
            }
        } else {
#pragma unroll
            for (int e = 0; e < 16; e++) fv[e] = (nb + e < N3) ? xs[e] : 0.f;
        }
        if (head > 0) {
            const float* pb = pacc + (size_t)b * SPLIT * DV * NP + (size_t)sc_ * NP + nb;
            float* hw = h + ((size_t)b * C_ + (head - 1) * DV + sc_) * N3 + nb;
            const size_t zs = (size_t)DV * NP;
            if (fullblk) {
#pragma unroll
                for (int e4 = 0; e4 < 4; e4++) {
                    float4 a0 = ((const float4*)(pb         ))[e4];
                    float4 a1 = ((const float4*)(pb +     zs))[e4];
                    float4 a2 = ((const float4*)(pb + 2 * zs))[e4];
                    float4 a3 = ((const float4*)(pb + 3 * zs))[e4];
                    float hc[4];
                    hc[0] = (a0.x + a1.x + a2.x + a3.x) * linv_s[sng + 4*e4 + 0];
                    hc[1] = (a0.y + a1.y + a2.y + a3.y) * linv_s[sng + 4*e4 + 1];
                    hc[2] = (a0.z + a1.z + a2.z + a3.z) * linv_s[sng + 4*e4 + 2];
                    hc[3] = (a0.w + a1.w + a2.w + a3.w) * linv_s[sng + 4*e4 + 3];
                    *(float4*)&hw[4*e4] = make_float4(hc[0], hc[1], hc[2], hc[3]);
                    fv[4*e4+0] += hc[0]; fv[4*e4+1] += hc[1];
                    fv[4*e4+2] += hc[2]; fv[4*e4+3] += hc[3];
                }
            } else {
#pragma unroll
                for (int e = 0; e < 16; e++) {
                    if (nb + e < N3) {
                        float a = pb[e] + pb[e + zs] + pb[e + 2*zs] + pb[e + 3*zs];
                        float hc = a * linv_s[sng + e];
                        hw[e] = hc;
                        fv[e] += hc;
                    }
                }
            }
        }
#pragma unroll
        for (int e = 0; e < 16; e++) {
            short hi = f2bf(fv[e]);
            short lo = f2bf(fv[e] - bf2f(hi));
            fhi[sng + e][sc_] = hi;
            flo[sng + e][sc_] = lo;
        }
    }
    __syncthreads();

    // ---- GEMM: 6 o-subtiles x this wave's n-subtile, K=64 ----
    float4v acc[6];
#pragma unroll
    for (int os = 0; os < 6; os++) acc[os] = (float4v){0.f, 0.f, 0.f, 0.f};

    const short* wqh = wqhi + head * QKVO * 64;
    const short* wql = wqlo + head * QKVO * 64;
#pragma unroll
    for (int ck = 0; ck < 2; ck++) {
        short8v bh = *(const short8v*)&fhi[w * 16 + ln][ck * 32 + g * 8];
        short8v bl = *(const short8v*)&flo[w * 16 + ln][ck * 32 + g * 8];
#pragma unroll
        for (int os = 0; os < 6; os++) {
            size_t off = (size_t)(os * 16 + ln) * 64 + ck * 32 + g * 8;
            short8v wh = *(const short8v*)(wqh + off);
            short8v wl = *(const short8v*)(wql + off);
            acc[os] = __builtin_amdgcn_mfma_f32_16x16x32_bf16(wh, bh, acc[os], 0, 0, 0);
            acc[os] = __builtin_amdgcn_mfma_f32_16x16x32_bf16(wh, bl, acc[os], 0, 0, 0);
            acc[os] = __builtin_amdgcn_mfma_f32_16x16x32_bf16(wl, bh, acc[os], 0, 0, 0);
        }
    }

    // ---- epilogue: D[o = os*16+g*4+r][n = n0+w*16+ln] ----
    const int n_ = n0 + w * 16 + ln;          // < NP always
    const bool ok = n_ < N3;
    float* qo = q0 + (size_t)b * KD * NP;
    short* ko = kbf + (size_t)b * NP * 16 + (size_t)n_ * 16;
    short* vo = vbf + (size_t)b * DV * NP;
#pragma unroll
    for (int os = 0; os < 6; os++) {
#pragma unroll
        for (int r = 0; r < 4; r++) {
            int o = os * 16 + g * 4 + r;
            float y = ok ? acc[os][r] + bsh[o] : 0.f;
            if (o < KD)            qo[(size_t)o * NP + n_] = y;
            else if (o < 2 * KD)   ko[o - KD] = f2bf(y);
            else                   vo[(size_t)(o - 2 * KD) * NP + n_] = f2bf(y);
        }
    }
}

// ---------------------------------------------------------------------------
// Depthwise 5x5x5 SAME conv: zero-padded 18^3 LDS volume, branchless.
// grid (KD, B), block 256
// ---------------------------------------------------------------------------
__global__ __launch_bounds__(256)
void dwconv_kernel(float* __restrict__ q0, const float* __restrict__ Wdw,
                   const float* __restrict__ dsc, const float* __restrict__ dbi,
                   int head)
{
    __shared__ float pv[18 * 18 * 18];
    int b = blockIdx.y, c = blockIdx.x;
    int t = threadIdx.x;
    float* qc = q0 + ((size_t)b * KD + c) * NP;

    for (int i = t; i < 5832; i += 256) pv[i] = 0.f;
    __syncthreads();
    for (int i = t; i < N3; i += 256) {
        int xx = i / R2; int rem = i - xx * R2; int yy = rem / R_; int zz = rem - yy * R_;
        pv[(xx + 2) * 324 + (yy + 2) * 18 + (zz + 2)] = qc[i];
    }
    __syncthreads();

    const float* w = Wdw + (head * KD + c) * 125;
    float scl = dsc[head * KD + c], bia = dbi[head * KD + c];

    if (t < R2) {
        int x = t / R_, y = t - (t / R_) * R_;
        float acc[14];
#pragma unroll
        for (int z = 0; z < 14; z++) acc[z] = 0.f;
#pragma unroll
        for (int a = 0; a < 5; a++) {
#pragma unroll
            for (int bb = 0; bb < 5; bb++) {
                const float* base = &pv[(x + a) * 324 + (y + bb) * 18];
                float col[18];
#pragma unroll
                for (int j = 0; j < 18; j++) col[j] = base[j];
#pragma unroll
                for (int cc = 0; cc < 5; cc++) {
                    float wv = w[a * 25 + bb * 5 + cc];
#pragma unroll
                    for (int z = 0; z < 14; z++) acc[z] += wv * col[z + cc];
                }
            }
        }
        float* qo = qc + x * R2 + y * R_;
#pragma unroll
        for (int z = 0; z < 14; z++) qo[z] = acc[z] * scl + bia;
    }
}

// ---------------------------------------------------------------------------
// Attention partial: r12-proven softmax (libm exp2f — raw v_exp_f32 is
// CONVICTED, do not reintroduce) + T14 register prefetch (r9-proven staging:
// next tile's K/V loads issued before the compute phase, latency hidden).
// grid (43, B, SPLIT), block 256.
// ---------------------------------------------------------------------------
__global__ __launch_bounds__(256, 4)
void attn_partial(const float* __restrict__ q0, const short* __restrict__ kbf,
                  const short* __restrict__ vbf, float* __restrict__ pacc,
                  float* __restrict__ pl, const float* __restrict__ abias, int head)
{
    __shared__ short ktT[64][40];      // [m][d], d 0..15 real, 16..31 zeros, pad->40
    __shared__ short vtT[64][72];      // [c][m], pad 72
    __shared__ short plds[4][16][72];  // per-wave P [n][m]
    __shared__ int   mxa[64];
    __shared__ float ab2[ABSZ];        // bias*log2e; [196..405] = -20000 sentinel

    const int b = blockIdx.y, z = blockIdx.z;
    const int qbase = blockIdx.x * 64;
    const int t = threadIdx.x;
    const int w = t >> 6;
    const int l = t & 63;
    const int g = l >> 4;
    const int ln = l & 15;

    for (int i = t; i < ABSZ; i += 256)
        ab2[i] = (i < 196) ? abias[head * R2 + i] * LOG2E : -20000.0f;

    const float* qq  = q0  + (size_t)b * KD * NP;
    const short* kbs = kbf + (size_t)b * NP * 16;
    const short* vbs = vbf + (size_t)b * DV * NP;

    // zero-fill ktT d=16..31 (in-loop staging only writes d<16)
    {
        int mm = t & 63, dg = t >> 6;
        short4v zz = {0, 0, 0, 0};
        *(short4v*)&ktT[mm][16 + dg * 4] = zz;
    }

    const int n_my = qbase + w * 16 + ln;
    short8v qf;
#pragma unroll
    for (int j = 0; j < 8; j++) {
        int d = g * 8 + j;
        qf[j] = (d < KD) ? f2bf(qq[(size_t)d * NP + n_my]) : (short)0;
    }
    const int nmc = n_my < N3 ? n_my : 0;
    const int nx = nmc / R2, ny = (nmc - nx * R2) / R_;

    float4v acc[4];
#pragma unroll
    for (int cs = 0; cs < 4; cs++) acc[cs] = (float4v){0.f, 0.f, 0.f, 0.f};
    float lsum = 0.f;

    // T14 prefetch registers (staging split: row smm, quarter sq)
    const int smm = t >> 2, sq = t & 3;
    short4v kpre;
    short8v vpre0, vpre1;
    {
        const int m0 = (z * TPC) * MT;
        kpre = *(const short4v*)(kbs + (size_t)(m0 + smm) * 16 + sq * 4);
        const short* vs = vbs + (size_t)smm * NP + m0 + sq * 16;
        vpre0 = ((const short8v*)vs)[0];
        vpre1 = ((const short8v*)vs)[1];
    }

    const int tEnd = min(z * TPC + TPC, NTILE);
    for (int t0 = z * TPC; t0 < tEnd; t0++) {
        const int m0 = t0 * MT;
        __syncthreads();                       // prev tile's LDS reads done
        *(short4v*)&ktT[smm][sq * 4]      = kpre;
        *(short8v*)&vtT[smm][sq * 16]     = vpre0;
        *(short8v*)&vtT[smm][sq * 16 + 8] = vpre1;
        if (t < 64) {
            int m = m0 + t;
            int mx, my;
            if (m < N3) { mx = m / R2; int rem = m - mx * R2; my = rem / R_; }
            else        { mx = 27; my = 27; }   // sentinel: idx in [210,405] -> -20000
            mxa[t] = (mx << 8) | my;
        }
        if (t0 + 1 < tEnd) {                   // prefetch next tile (in flight
            const int m1 = (t0 + 1) * MT;      //  across the compute phase)
            kpre = *(const short4v*)(kbs + (size_t)(m1 + smm) * 16 + sq * 4);
            const short* vs = vbs + (size_t)smm * NP + m1 + sq * 16;
            vpre0 = ((const short8v*)vs)[0];
            vpre1 = ((const short8v*)vs)[1];
        }
        __syncthreads();                       // tile staged

        // ---- QK^T + softmax (guard-free, clamp-free) ----
#pragma unroll
        for (int ms = 0; ms < 4; ms++) {
            short8v af = *(const short8v*)&ktT[ms * 16 + ln][g * 8];
            float4v zf = {0.f, 0.f, 0.f, 0.f};
            float4v s = __builtin_amdgcn_mfma_f32_16x16x32_bf16(af, qf, zf, 0, 0, 0);
            int4 pk4 = *(const int4*)&mxa[ms * 16 + g * 4];
            int pka[4] = {pk4.x, pk4.y, pk4.z, pk4.w};
            float p[4];
#pragma unroll
            for (int r = 0; r < 4; r++) {
                int mx = pka[r] >> 8, my = pka[r] & 255;
                int dx, idx;
                asm("v_sad_u32 %0, %1, %2, 0" : "=v"(dx) : "v"(nx), "v"(mx));
                int t14 = dx * 14;
                asm("v_sad_u32 %0, %1, %2, %3" : "=v"(idx) : "v"(ny), "v"(my), "v"(t14));
                float lg2 = fmaf(s[r], SC2, ab2[idx]);
                p[r] = exp2f(lg2);
                lsum += p[r];
            }
            unsigned pk01, pk23;
            asm("v_cvt_pk_bf16_f32 %0, %1, %2" : "=v"(pk01) : "v"(p[0]), "v"(p[1]));
            asm("v_cvt_pk_bf16_f32 %0, %1, %2" : "=v"(pk23) : "v"(p[2]), "v"(p[3]));
            uint2 pw = make_uint2(pk01, pk23);
            *(uint2*)&plds[w][ln][ms * 16 + g * 4] = pw;
        }

        // ---- PV ----
#pragma unroll
        for (int ck = 0; ck < 2; ck++) {
            short8v pa = *(const short8v*)&plds[w][ln][ck * 32 + g * 8];
#pragma unroll
            for (int cs = 0; cs < 4; cs++) {
                short8v vf = *(const short8v*)&vtT[cs * 16 + ln][ck * 32 + g * 8];
                acc[cs] = __builtin_amdgcn_mfma_f32_16x16x32_bf16(pa, vf, acc[cs], 0, 0, 0);
            }
        }
    }

    // ---- epilogue (proven) ----
    lsum += __shfl_xor(lsum, 16);
    lsum += __shfl_xor(lsum, 32);

    float* pbase = pacc + (size_t)(b * SPLIT + z) * DV * NP;
    if (l < 16) {
        int n_l = qbase + w * 16 + l;
        if (n_l < N3) pl[(size_t)(b * SPLIT + z) * NP + n_l] = lsum;
    }
    const int n0w = qbase + w * 16 + g * 4;
    if (n0w < N3) {
#pragma unroll
        for (int cs = 0; cs < 4; cs++) {
            int c = cs * 16 + ln;
            *(float4v*)&pbase[(size_t)c * NP + n0w] = acc[cs];
        }
    }
}

// ---------------------------------------------------------------------------
// Projection: split-bf16 MFMA + fused combine of head 3 (channels 192..255
// computed inline from pacc/pl — same fp32 sum order as the combine kernel).
// grid (43 n-tiles, B), block 256
// ---------------------------------------------------------------------------
__global__ __launch_bounds__(256, 2)
void proj_kernel(const float* __restrict__ h, const float* __restrict__ pacc,
                 const float* __restrict__ pl, const short* __restrict__ whi,
                 const short* __restrict__ wlo, const float* __restrict__ psc,
                 const float* __restrict__ pbi, float* __restrict__ out)
{
    __shared__ short hhi[64][40];
    __shared__ short hlo[64][40];
    __shared__ float linv_s[64];

    const int b = blockIdx.y;
    const int n0 = blockIdx.x * 64;
    const int t = threadIdx.x;
    const int w = t >> 6, l = t & 63, g = l >> 4, ln = l & 15;

    if (t < 64) {   // 1/sum(l) for head 3 (used by the c0>=192 chunks)
        int n = n0 + t;
        float lt = pl[(size_t)(b * SPLIT + 0) * NP + n]
                 + pl[(size_t)(b * SPLIT + 1) * NP + n]
                 + pl[(size_t)(b * SPLIT + 2) * NP + n]
                 + pl[(size_t)(b * SPLIT + 3) * NP + n];
        linv_s[t] = 1.f / lt;   // garbage for pad n (gated below)
    }

    float4v acc[4][4];
#pragma unroll
    for (int os = 0; os < 4; os++)
#pragma unroll
        for (int ns = 0; ns < 4; ns++) acc[os][ns] = (float4v){0.f, 0.f, 0.f, 0.f};

    const float* hb = h + (size_t)b * C_ * N3;
    const int sc = t >> 3;
    const int sn = (t & 7) * 8;

    for (int c0 = 0; c0 < 256; c0 += 32) {
        __syncthreads();
        if (c0 < 192) {   // heads 0..2: h already materialized
            const float* hsrc = hb + (size_t)(c0 + sc) * N3 + n0 + sn;
            float4 f0 = ((const float4*)hsrc)[0];
            float4 f1 = ((const float4*)hsrc)[1];
            float va[8] = { f0.x, f0.y, f0.z, f0.w, f1.x, f1.y, f1.z, f1.w };
#pragma unroll
            for (int u = 0; u < 8; u++) {
                float v = va[u] > 0.f ? va[u] : 0.f;
                short hi = f2bf(v);
                short lo = f2bf(v - bf2f(hi));
                hhi[sn + u][sc] = hi;
                hlo[sn + u][sc] = lo;
            }
        } else {          // head 3: fused combine from partials
            const int cl = c0 + sc - 192;     // head-3 local channel
            const int nb = n0 + sn;
            const bool in = nb < N3;          // N3 % 8 == 0: per-8 all-in or all-out
            float va[8] = {0,0,0,0,0,0,0,0};
            if (in) {
                const float* pb = pacc + (size_t)b * SPLIT * DV * NP + (size_t)cl * NP + nb;
                const size_t zs = (size_t)DV * NP;
#pragma unroll
                for (int e4 = 0; e4 < 2; e4++) {
                    float4 a0 = ((const float4*)(pb         ))[e4];
                    float4 a1 = ((const float4*)(pb +     zs))[e4];
                    float4 a2 = ((const float4*)(pb + 2 * zs))[e4];
                    float4 a3 = ((const float4*)(pb + 3 * zs))[e4];
                    va[4*e4+0] = (a0.x + a1.x + a2.x + a3.x) * linv_s[sn + 4*e4 + 0];
                    va[4*e4+1] = (a0.y + a1.y + a2.y + a3.y) * linv_s[sn + 4*e4 + 1];
                    va[4*e4+2] = (a0.z + a1.z + a2.z + a3.z) * linv_s[sn + 4*e4 + 2];
                    va[4*e4+3] = (a0.w + a1.w + a2.w + a3.w) * linv_s[sn + 4*e4 + 3];
                }
            }
#pragma unroll
            for (int u = 0; u < 8; u++) {
                float v = va[u] > 0.f ? va[u] : 0.f;
                short hi = f2bf(v);
                short lo = f2bf(v - bf2f(hi));
                hhi[sn + u][sc] = hi;
                hlo[sn + u][sc] = lo;
            }
        }
        __syncthreads();

        short8v wh[4], wl[4];
#pragma unroll
        for (int os = 0; os < 4; os++) {
            size_t off = (size_t)(64 * w + os * 16 + ln) * 256 + c0 + g * 8;
            wh[os] = *(const short8v*)(whi + off);
            wl[os] = *(const short8v*)(wlo + off);
        }
#pragma unroll
        for (int ns = 0; ns < 4; ns++) {
            short8v bh = *(const short8v*)&hhi[ns * 16 + ln][g * 8];
            short8v bl = *(const short8v*)&hlo[ns * 16 + ln][g * 8];
#pragma unroll
            for (int os = 0; os < 4; os++) {
                acc[os][ns] = __builtin_amdgcn_mfma_f32_16x16x32_bf16(wh[os], bh, acc[os][ns], 0, 0, 0);
                acc[os][ns] = __builtin_amdgcn_mfma_f32_16x16x32_bf16(wh[os], bl, acc[os][ns], 0, 0, 0);
                acc[os][ns] = __builtin_amdgcn_mfma_f32_16x16x32_bf16(wl[os], bh, acc[os][ns], 0, 0, 0);
            }
        }
    }

    float* ob = out + (size_t)b * C_ * N3;
#pragma unroll
    for (int os = 0; os < 4; os++) {
#pragma unroll
        for (int r = 0; r < 4; r++) {
            int o = 64 * w + os * 16 + g * 4 + r;
            float s0 = psc[o], b0 = pbi[o];
#pragma unroll
            for (int ns = 0; ns < 4; ns++) {
                int n = n0 + ns * 16 + ln;
                if (n < N3) ob[(size_t)o * N3 + n] = acc[os][ns][r] * s0 + b0;
            }
        }
    }
}

// ---------------------------------------------------------------------------
extern "C" void kernel_launch(void* const* d_in, const int* in_sizes, int n_in,
                              void* d_out, int out_size, void* d_ws, size_t ws_size,
                              hipStream_t stream)
{
    const float* x    = (const float*)d_in[0];
    const float* Wqkv = (const float*)d_in[1];
    const float* qsc  = (const float*)d_in[2];
    const float* qbi  = (const float*)d_in[3];
    const float* Wdw  = (const float*)d_in[4];
    const float* dsc  = (const float*)d_in[5];
    const float* dbi  = (const float*)d_in[6];
    const float* Wp   = (const float*)d_in[7];
    const float* psc  = (const float*)d_in[8];
    const float* pbi  = (const float*)d_in[9];
    const float* ab   = (const float*)d_in[10];
    // d_in[11] = bias_idx: unused (computed analytically)

    float* out = (float*)d_out;
    char*  wsb = (char*)d_ws;
    float* q0   = (float*)wsb;                                  // B*KD*NP f32
    short* kbf  = (short*)(q0 + (size_t)B_ * KD * NP);          // B*NP*16 bf16
    short* vbf  = kbf + (size_t)B_ * NP * 16;                   // B*DV*NP bf16
    float* h    = (float*)(vbf + (size_t)B_ * DV * NP);         // B*C*N3 f32
    float* pacc = h + (size_t)B_ * C_ * N3;                     // B*SPLIT*DV*NP f32
    float* pl   = pacc + (size_t)B_ * SPLIT * DV * NP;          // B*SPLIT*NP f32
    short* whi  = (short*)(pl + (size_t)B_ * SPLIT * NP);       // 256*256 bf16
    short* wlo  = whi + 256 * 256;                              // 256*256 bf16
    short* wqhi = wlo + 256 * 256;                              // 4*96*64 bf16
    short* wqlo = wqhi + NH * QKVO * 64;                        // 4*96*64 bf16

    wprep_kernel<<<256, 256, 0, stream>>>(Wp, whi, wlo, Wqkv, qsc, wqhi, wqlo);

    for (int head = 0; head < NH; head++) {
        qkv_mfma<<<dim3(43, B_), 256, 0, stream>>>(x, h, pacc, pl, wqhi, wqlo, qbi,
                                                   q0, kbf, vbf, head);
        dwconv_kernel<<<dim3(KD, B_), 256, 0, stream>>>(q0, Wdw, dsc, dbi, head);
        attn_partial<<<dim3(43, B_, SPLIT), 256, 0, stream>>>(q0, kbf, vbf, pacc, pl, ab, head);
    }
    proj_kernel<<<dim3(43, B_), 256, 0, stream>>>(h, pacc, pl, whi, wlo, psc, pbi, out);
}

// Round 15
// 318.919 us; speedup vs baseline: 1.0692x; 1.0585x over previous
//
#include <hip/hip_runtime.h>

#define B_    8
#define C_    256
#define R_    14
#define R2    196
#define N3    2744     // 14^3
#define NP    2752     // padded (43*64): guard-free tile staging
#define NH    4
#define KD    16
#define DV    64
#define QKVO  96       // 2*KD + DV
#define MT    64       // m-tile in attention
#define NTILE 43
#define SPLIT 4
#define TPC   11       // tiles per m-chunk

#define SC2   0.36067376f   // 0.25 * log2(e)
#define LOG2E 1.44269504f
#define ABSZ  406           // 196 real + sentinel region (-20000)

typedef __attribute__((ext_vector_type(8))) short short8v;
typedef __attribute__((ext_vector_type(4))) short short4v;
typedef __attribute__((ext_vector_type(4))) float float4v;

__device__ __forceinline__ int iabs(int v){ return v < 0 ? -v : v; }

// fp32 -> bf16 round-to-nearest-even (finite inputs)
__device__ __forceinline__ short f2bf(float f){
    union { float f; unsigned int u; } c; c.f = f;
    return (short)((c.u + 0x7FFFu + ((c.u >> 16) & 1u)) >> 16);
}
__device__ __forceinline__ float bf2f(short s){
    union { unsigned int u; float f; } c; c.u = ((unsigned int)(unsigned short)s) << 16;
    return c.f;
}

// ---------------------------------------------------------------------------
// wprep: Wp -> bf16 hi/lo split; Wqkv*qkv_scale -> bf16 hi/lo split.
// grid 256, block 256 (i < 65536)
// ---------------------------------------------------------------------------
__global__ __launch_bounds__(256)
void wprep_kernel(const float* __restrict__ Wp, short* __restrict__ whi,
                  short* __restrict__ wlo, const float* __restrict__ Wqkv,
                  const float* __restrict__ qsc, short* __restrict__ wqhi,
                  short* __restrict__ wqlo)
{
    int i = blockIdx.x * 256 + threadIdx.x;   // 65536 total
    {
        float w = Wp[i];
        short hi = f2bf(w);
        short lo = f2bf(w - bf2f(hi));
        whi[i] = hi; wlo[i] = lo;
    }
    if (i < NH * QKVO * 64) {                 // 24576
        int o_all = i >> 6;                   // head*96 + o
        float w = Wqkv[i] * qsc[o_all];       // fold scale into W rows
        short hi = f2bf(w);
        short lo = f2bf(w - bf2f(hi));
        wqhi[i] = hi; wqlo[i] = lo;
    }
}

// ---------------------------------------------------------------------------
// QKV: split-bf16 MFMA GEMM + fused combine of PREVIOUS head's partials.
// grid (43, B), block 256
// ---------------------------------------------------------------------------
__global__ __launch_bounds__(256, 2)
void qkv_mfma(const float* __restrict__ x, float* __restrict__ h,
              const float* __restrict__ pacc, const float* __restrict__ pl,
              const short* __restrict__ wqhi, const short* __restrict__ wqlo,
              const float* __restrict__ qbi,
              float* __restrict__ q0, short* __restrict__ kbf, short* __restrict__ vbf,
              int head)
{
    __shared__ short fhi[64][72];   // [n][c] feat hi
    __shared__ short flo[64][72];   // [n][c] feat lo
    __shared__ float bsh[96];
    __shared__ float linv_s[64];

    const int b = blockIdx.y;
    const int n0 = blockIdx.x * 64;
    const int t = threadIdx.x;
    const int w = t >> 6, l = t & 63, g = l >> 4, ln = l & 15;

    if (t < 96) bsh[t] = qbi[head * QKVO + t];

    if (head > 0) {               // stage 1/sum(l) for this n-tile
        if (t < 64) {
            int n = n0 + t;
            float lt = pl[(size_t)(b * SPLIT + 0) * NP + n]
                     + pl[(size_t)(b * SPLIT + 1) * NP + n]
                     + pl[(size_t)(b * SPLIT + 2) * NP + n]
                     + pl[(size_t)(b * SPLIT + 3) * NP + n];
            linv_s[t] = 1.f / lt;  // garbage for pad n (unused)
        }
        __syncthreads();
    }

    // ---- stage feat transposed, hi/lo split: thread = (c = t&63, n-group) ----
    {
        const int sc_ = t & 63;
        const int sng = (t >> 6) * 16;        // n local base
        const int nb = n0 + sng;
        const float* xs = x + ((size_t)b * C_ + head * DV + sc_) * N3 + nb;
        float fv[16];
        const bool fullblk = (nb + 15 < N3);
        if (fullblk) {
#pragma unroll
            for (int e4 = 0; e4 < 4; e4++) {
                float4 xv = ((const float4*)xs)[e4];
                fv[4*e4+0] = xv.x; fv[4*e4+1] = xv.y; fv[4*e4+2] = xv.z; fv[4*e4+3] = xv.w;
            }
        } else {
#pragma unroll
            for (int e = 0; e < 16; e++) fv[e] = (nb + e < N3) ? xs[e] : 0.f;
        }
        if (head > 0) {
            const float* pb = pacc + (size_t)b * SPLIT * DV * NP + (size_t)sc_ * NP + nb;
            float* hw = h + ((size_t)b * C_ + (head - 1) * DV + sc_) * N3 + nb;
            const size_t zs = (size_t)DV * NP;
            if (fullblk) {
#pragma unroll
                for (int e4 = 0; e4 < 4; e4++) {
                    float4 a0 = ((const float4*)(pb         ))[e4];
                    float4 a1 = ((const float4*)(pb +     zs))[e4];
                    float4 a2 = ((const float4*)(pb + 2 * zs))[e4];
                    float4 a3 = ((const float4*)(pb + 3 * zs))[e4];
                    float hc[4];
                    hc[0] = (a0.x + a1.x + a2.x + a3.x) * linv_s[sng + 4*e4 + 0];
                    hc[1] = (a0.y + a1.y + a2.y + a3.y) * linv_s[sng + 4*e4 + 1];
                    hc[2] = (a0.z + a1.z + a2.z + a3.z) * linv_s[sng + 4*e4 + 2];
                    hc[3] = (a0.w + a1.w + a2.w + a3.w) * linv_s[sng + 4*e4 + 3];
                    *(float4*)&hw[4*e4] = make_float4(hc[0], hc[1], hc[2], hc[3]);
                    fv[4*e4+0] += hc[0]; fv[4*e4+1] += hc[1];
                    fv[4*e4+2] += hc[2]; fv[4*e4+3] += hc[3];
                }
            } else {
#pragma unroll
                for (int e = 0; e < 16; e++) {
                    if (nb + e < N3) {
                        float a = pb[e] + pb[e + zs] + pb[e + 2*zs] + pb[e + 3*zs];
                        float hc = a * linv_s[sng + e];
                        hw[e] = hc;
                        fv[e] += hc;
                    }
                }
            }
        }
#pragma unroll
        for (int e = 0; e < 16; e++) {
            short hi = f2bf(fv[e]);
            short lo = f2bf(fv[e] - bf2f(hi));
            fhi[sng + e][sc_] = hi;
            flo[sng + e][sc_] = lo;
        }
    }
    __syncthreads();

    // ---- GEMM: 6 o-subtiles x this wave's n-subtile, K=64 ----
    float4v acc[6];
#pragma unroll
    for (int os = 0; os < 6; os++) acc[os] = (float4v){0.f, 0.f, 0.f, 0.f};

    const short* wqh = wqhi + head * QKVO * 64;
    const short* wql = wqlo + head * QKVO * 64;
#pragma unroll
    for (int ck = 0; ck < 2; ck++) {
        short8v bh = *(const short8v*)&fhi[w * 16 + ln][ck * 32 + g * 8];
        short8v bl = *(const short8v*)&flo[w * 16 + ln][ck * 32 + g * 8];
#pragma unroll
        for (int os = 0; os < 6; os++) {
            size_t off = (size_t)(os * 16 + ln) * 64 + ck * 32 + g * 8;
            short8v wh = *(const short8v*)(wqh + off);
            short8v wl = *(const short8v*)(wql + off);
            acc[os] = __builtin_amdgcn_mfma_f32_16x16x32_bf16(wh, bh, acc[os], 0, 0, 0);
            acc[os] = __builtin_amdgcn_mfma_f32_16x16x32_bf16(wh, bl, acc[os], 0, 0, 0);
            acc[os] = __builtin_amdgcn_mfma_f32_16x16x32_bf16(wl, bh, acc[os], 0, 0, 0);
        }
    }

    // ---- epilogue: D[o = os*16+g*4+r][n = n0+w*16+ln] ----
    const int n_ = n0 + w * 16 + ln;          // < NP always
    const bool ok = n_ < N3;
    float* qo = q0 + (size_t)b * KD * NP;
    short* ko = kbf + (size_t)b * NP * 16 + (size_t)n_ * 16;
    short* vo = vbf + (size_t)b * DV * NP;
#pragma unroll
    for (int os = 0; os < 6; os++) {
#pragma unroll
        for (int r = 0; r < 4; r++) {
            int o = os * 16 + g * 4 + r;
            float y = ok ? acc[os][r] + bsh[o] : 0.f;
            if (o < KD)            qo[(size_t)o * NP + n_] = y;
            else if (o < 2 * KD)   ko[o - KD] = f2bf(y);
            else                   vo[(size_t)(o - 2 * KD) * NP + n_] = f2bf(y);
        }
    }
}

// ---------------------------------------------------------------------------
// Depthwise 5x5x5 SAME conv: zero-padded 18^3 LDS volume, branchless.
// grid (KD, B), block 256
// ---------------------------------------------------------------------------
__global__ __launch_bounds__(256)
void dwconv_kernel(float* __restrict__ q0, const float* __restrict__ Wdw,
                   const float* __restrict__ dsc, const float* __restrict__ dbi,
                   int head)
{
    __shared__ float pv[18 * 18 * 18];
    int b = blockIdx.y, c = blockIdx.x;
    int t = threadIdx.x;
    float* qc = q0 + ((size_t)b * KD + c) * NP;

    for (int i = t; i < 5832; i += 256) pv[i] = 0.f;
    __syncthreads();
    for (int i = t; i < N3; i += 256) {
        int xx = i / R2; int rem = i - xx * R2; int yy = rem / R_; int zz = rem - yy * R_;
        pv[(xx + 2) * 324 + (yy + 2) * 18 + (zz + 2)] = qc[i];
    }
    __syncthreads();

    const float* w = Wdw + (head * KD + c) * 125;
    float scl = dsc[head * KD + c], bia = dbi[head * KD + c];

    if (t < R2) {
        int x = t / R_, y = t - (t / R_) * R_;
        float acc[14];
#pragma unroll
        for (int z = 0; z < 14; z++) acc[z] = 0.f;
#pragma unroll
        for (int a = 0; a < 5; a++) {
#pragma unroll
            for (int bb = 0; bb < 5; bb++) {
                const float* base = &pv[(x + a) * 324 + (y + bb) * 18];
                float col[18];
#pragma unroll
                for (int j = 0; j < 18; j++) col[j] = base[j];
#pragma unroll
                for (int cc = 0; cc < 5; cc++) {
                    float wv = w[a * 25 + bb * 5 + cc];
#pragma unroll
                    for (int z = 0; z < 14; z++) acc[z] += wv * col[z + cc];
                }
            }
        }
        float* qo = qc + x * R2 + y * R_;
#pragma unroll
        for (int z = 0; z < 14; z++) qo[z] = acc[z] * scl + bia;
    }
}

// ---------------------------------------------------------------------------
// Attention partial v15: bias via per-tile 6x8 patch (bias depends only on
// (n/14, m/14) -> <=36 distinct values per block-tile). Per-logit path:
// 1 add + broadcast-heavy 48-entry LDS gather + fma + exp2f (frozen numerics).
// grid (43, B, SPLIT), block 256.
// ---------------------------------------------------------------------------
__global__ __launch_bounds__(256, 4)
void attn_partial(const float* __restrict__ q0, const short* __restrict__ kbf,
                  const short* __restrict__ vbf, float* __restrict__ pacc,
                  float* __restrict__ pl, const float* __restrict__ abias, int head)
{
    __shared__ short ktT[64][40];      // [m][d], d 0..15 real, 16..31 zeros, pad->40
    __shared__ short vtT[64][72];      // [c][m], pad 72
    __shared__ short plds[4][16][72];  // per-wave P [n][m]
    __shared__ int   mja[64];          // per-m mjloc (0..5 real; 6 pad)
    __shared__ float patch[6][8];      // [nj][mj] bias*log2e; mj 6,7 = -20000
    __shared__ float ab2[ABSZ];        // bias*log2e; [196..405] = -20000 sentinel

    const int b = blockIdx.y, z = blockIdx.z;
    const int qbase = blockIdx.x * 64;
    const int t = threadIdx.x;
    const int w = t >> 6;
    const int l = t & 63;
    const int g = l >> 4;
    const int ln = l & 15;

    for (int i = t; i < ABSZ; i += 256)
        ab2[i] = (i < 196) ? abias[head * R2 + i] * LOG2E : -20000.0f;

    const float* qq  = q0  + (size_t)b * KD * NP;
    const short* kbs = kbf + (size_t)b * NP * 16;
    const short* vbs = vbf + (size_t)b * DV * NP;

    // zero-fill ktT d=16..31 (in-loop staging only writes d<16)
    {
        int mm = t & 63, dg = t >> 6;
        short4v zz = {0, 0, 0, 0};
        *(short4v*)&ktT[mm][16 + dg * 4] = zz;
    }

    const int n_my = qbase + w * 16 + ln;
    short8v qf;
#pragma unroll
    for (int j = 0; j < 8; j++) {
        int d = g * 8 + j;
        qf[j] = (d < KD) ? f2bf(qq[(size_t)d * NP + n_my]) : (short)0;
    }
    const int nxy0 = qbase / 14;
    const int njbase = (n_my / 14 - nxy0) * 8;   // per-lane constant, in [0,40]

    float4v acc[4];
#pragma unroll
    for (int cs = 0; cs < 4; cs++) acc[cs] = (float4v){0.f, 0.f, 0.f, 0.f};
    float lsum = 0.f;

    // T14 prefetch registers (staging split: row smm, quarter sq)
    const int smm = t >> 2, sq = t & 3;
    short4v kpre;
    short8v vpre0, vpre1;
    {
        const int m0 = (z * TPC) * MT;
        kpre = *(const short4v*)(kbs + (size_t)(m0 + smm) * 16 + sq * 4);
        const short* vs = vbs + (size_t)smm * NP + m0 + sq * 16;
        vpre0 = ((const short8v*)vs)[0];
        vpre1 = ((const short8v*)vs)[1];
    }

    const int tEnd = min(z * TPC + TPC, NTILE);
    for (int t0 = z * TPC; t0 < tEnd; t0++) {
        const int m0 = t0 * MT;
        __syncthreads();                       // prev tile's LDS reads done
        *(short4v*)&ktT[smm][sq * 4]      = kpre;
        *(short8v*)&vtT[smm][sq * 16]     = vpre0;
        *(short8v*)&vtT[smm][sq * 16 + 8] = vpre1;
        if (t < 64) {                          // per-m mj local index
            int m = m0 + t;
            mja[t] = (m < N3) ? (m / 14 - m0 / 14) : 6;
        } else if (t < 112) {                  // 6x8 bias patch for this tile
            int i = t - 64;
            int nj = i >> 3, mj = i & 7;
            float v = -20000.0f;
            if (mj < 6) {
                int nxy = nxy0 + nj;           // may reach 196 (pad rows, gated out)
                int mxy = m0 / 14 + mj;
                int nx = nxy / 14, ny2 = nxy - nx * 14;
                int mx = mxy / 14, my2 = mxy - mx * 14;
                int idx = iabs(nx - mx) * 14 + iabs(ny2 - my2);
                v = ab2[idx];
            }
            patch[nj][mj] = v;
        }
        if (t0 + 1 < tEnd) {                   // prefetch next tile
            const int m1 = (t0 + 1) * MT;
            kpre = *(const short4v*)(kbs + (size_t)(m1 + smm) * 16 + sq * 4);
            const short* vs = vbs + (size_t)smm * NP + m1 + sq * 16;
            vpre0 = ((const short8v*)vs)[0];
            vpre1 = ((const short8v*)vs)[1];
        }
        __syncthreads();                       // tile staged

        const float* pf = &patch[0][0];

        // ---- QK^T + softmax ----
#pragma unroll
        for (int ms = 0; ms < 4; ms++) {
            short8v af = *(const short8v*)&ktT[ms * 16 + ln][g * 8];
            float4v zf = {0.f, 0.f, 0.f, 0.f};
            float4v s = __builtin_amdgcn_mfma_f32_16x16x32_bf16(af, qf, zf, 0, 0, 0);
            int4 pk4 = *(const int4*)&mja[ms * 16 + g * 4];
            int pka[4] = {pk4.x, pk4.y, pk4.z, pk4.w};
            float p[4];
#pragma unroll
            for (int r = 0; r < 4; r++) {
                float bias = pf[njbase + pka[r]];     // broadcast-heavy gather
                float lg2 = fmaf(s[r], SC2, bias);
                p[r] = exp2f(lg2);
                lsum += p[r];
            }
            unsigned pk01, pk23;
            asm("v_cvt_pk_bf16_f32 %0, %1, %2" : "=v"(pk01) : "v"(p[0]), "v"(p[1]));
            asm("v_cvt_pk_bf16_f32 %0, %1, %2" : "=v"(pk23) : "v"(p[2]), "v"(p[3]));
            uint2 pw = make_uint2(pk01, pk23);
            *(uint2*)&plds[w][ln][ms * 16 + g * 4] = pw;
        }

        // ---- PV ----
#pragma unroll
        for (int ck = 0; ck < 2; ck++) {
            short8v pa = *(const short8v*)&plds[w][ln][ck * 32 + g * 8];
#pragma unroll
            for (int cs = 0; cs < 4; cs++) {
                short8v vf = *(const short8v*)&vtT[cs * 16 + ln][ck * 32 + g * 8];
                acc[cs] = __builtin_amdgcn_mfma_f32_16x16x32_bf16(pa, vf, acc[cs], 0, 0, 0);
            }
        }
    }

    // ---- epilogue (proven) ----
    lsum += __shfl_xor(lsum, 16);
    lsum += __shfl_xor(lsum, 32);

    float* pbase = pacc + (size_t)(b * SPLIT + z) * DV * NP;
    if (l < 16) {
        int n_l = qbase + w * 16 + l;
        if (n_l < N3) pl[(size_t)(b * SPLIT + z) * NP + n_l] = lsum;
    }
    const int n0w = qbase + w * 16 + g * 4;
    if (n0w < N3) {
#pragma unroll
        for (int cs = 0; cs < 4; cs++) {
            int c = cs * 16 + ln;
            *(float4v*)&pbase[(size_t)c * NP + n0w] = acc[cs];
        }
    }
}

// ---------------------------------------------------------------------------
// Projection: split-bf16 MFMA + fused combine of head 3 (channels 192..255
// computed inline from pacc/pl — same fp32 sum order as the combine kernel).
// grid (43 n-tiles, B), block 256
// ---------------------------------------------------------------------------
__global__ __launch_bounds__(256, 2)
void proj_kernel(const float* __restrict__ h, const float* __restrict__ pacc,
                 const float* __restrict__ pl, const short* __restrict__ whi,
                 const short* __restrict__ wlo, const float* __restrict__ psc,
                 const float* __restrict__ pbi, float* __restrict__ out)
{
    __shared__ short hhi[64][40];
    __shared__ short hlo[64][40];
    __shared__ float linv_s[64];

    const int b = blockIdx.y;
    const int n0 = blockIdx.x * 64;
    const int t = threadIdx.x;
    const int w = t >> 6, l = t & 63, g = l >> 4, ln = l & 15;

    if (t < 64) {   // 1/sum(l) for head 3 (used by the c0>=192 chunks)
        int n = n0 + t;
        float lt = pl[(size_t)(b * SPLIT + 0) * NP + n]
                 + pl[(size_t)(b * SPLIT + 1) * NP + n]
                 + pl[(size_t)(b * SPLIT + 2) * NP + n]
                 + pl[(size_t)(b * SPLIT + 3) * NP + n];
        linv_s[t] = 1.f / lt;   // garbage for pad n (gated below)
    }

    float4v acc[4][4];
#pragma unroll
    for (int os = 0; os < 4; os++)
#pragma unroll
        for (int ns = 0; ns < 4; ns++) acc[os][ns] = (float4v){0.f, 0.f, 0.f, 0.f};

    const float* hb = h + (size_t)b * C_ * N3;
    const int sc = t >> 3;
    const int sn = (t & 7) * 8;

    for (int c0 = 0; c0 < 256; c0 += 32) {
        __syncthreads();
        if (c0 < 192) {   // heads 0..2: h already materialized
            const float* hsrc = hb + (size_t)(c0 + sc) * N3 + n0 + sn;
            float4 f0 = ((const float4*)hsrc)[0];
            float4 f1 = ((const float4*)hsrc)[1];
            float va[8] = { f0.x, f0.y, f0.z, f0.w, f1.x, f1.y, f1.z, f1.w };
#pragma unroll
            for (int u = 0; u < 8; u++) {
                float v = va[u] > 0.f ? va[u] : 0.f;
                short hi = f2bf(v);
                short lo = f2bf(v - bf2f(hi));
                hhi[sn + u][sc] = hi;
                hlo[sn + u][sc] = lo;
            }
        } else {          // head 3: fused combine from partials
            const int cl = c0 + sc - 192;     // head-3 local channel
            const int nb = n0 + sn;
            const bool in = nb < N3;          // N3 % 8 == 0: per-8 all-in or all-out
            float va[8] = {0,0,0,0,0,0,0,0};
            if (in) {
                const float* pb = pacc + (size_t)b * SPLIT * DV * NP + (size_t)cl * NP + nb;
                const size_t zs = (size_t)DV * NP;
#pragma unroll
                for (int e4 = 0; e4 < 2; e4++) {
                    float4 a0 = ((const float4*)(pb         ))[e4];
                    float4 a1 = ((const float4*)(pb +     zs))[e4];
                    float4 a2 = ((const float4*)(pb + 2 * zs))[e4];
                    float4 a3 = ((const float4*)(pb + 3 * zs))[e4];
                    va[4*e4+0] = (a0.x + a1.x + a2.x + a3.x) * linv_s[sn + 4*e4 + 0];
                    va[4*e4+1] = (a0.y + a1.y + a2.y + a3.y) * linv_s[sn + 4*e4 + 1];
                    va[4*e4+2] = (a0.z + a1.z + a2.z + a3.z) * linv_s[sn + 4*e4 + 2];
                    va[4*e4+3] = (a0.w + a1.w + a2.w + a3.w) * linv_s[sn + 4*e4 + 3];
                }
            }
#pragma unroll
            for (int u = 0; u < 8; u++) {
                float v = va[u] > 0.f ? va[u] : 0.f;
                short hi = f2bf(v);
                short lo = f2bf(v - bf2f(hi));
                hhi[sn + u][sc] = hi;
                hlo[sn + u][sc] = lo;
            }
        }
        __syncthreads();

        short8v wh[4], wl[4];
#pragma unroll
        for (int os = 0; os < 4; os++) {
            size_t off = (size_t)(64 * w + os * 16 + ln) * 256 + c0 + g * 8;
            wh[os] = *(const short8v*)(whi + off);
            wl[os] = *(const short8v*)(wlo + off);
        }
#pragma unroll
        for (int ns = 0; ns < 4; ns++) {
            short8v bh = *(const short8v*)&hhi[ns * 16 + ln][g * 8];
            short8v bl = *(const short8v*)&hlo[ns * 16 + ln][g * 8];
#pragma unroll
            for (int os = 0; os < 4; os++) {
                acc[os][ns] = __builtin_amdgcn_mfma_f32_16x16x32_bf16(wh[os], bh, acc[os][ns], 0, 0, 0);
                acc[os][ns] = __builtin_amdgcn_mfma_f32_16x16x32_bf16(wh[os], bl, acc[os][ns], 0, 0, 0);
                acc[os][ns] = __builtin_amdgcn_mfma_f32_16x16x32_bf16(wl[os], bh, acc[os][ns], 0, 0, 0);
            }
        }
    }

    float* ob = out + (size_t)b * C_ * N3;
#pragma unroll
    for (int os = 0; os < 4; os++) {
#pragma unroll
        for (int r = 0; r < 4; r++) {
            int o = 64 * w + os * 16 + g * 4 + r;
            float s0 = psc[o], b0 = pbi[o];
#pragma unroll
            for (int ns = 0; ns < 4; ns++) {
                int n = n0 + ns * 16 + ln;
                if (n < N3) ob[(size_t)o * N3 + n] = acc[os][ns][r] * s0 + b0;
            }
        }
    }
}

// ---------------------------------------------------------------------------
extern "C" void kernel_launch(void* const* d_in, const int* in_sizes, int n_in,
                              void* d_out, int out_size, void* d_ws, size_t ws_size,
                              hipStream_t stream)
{
    const float* x    = (const float*)d_in[0];
    const float* Wqkv = (const float*)d_in[1];
    const float* qsc  = (const float*)d_in[2];
    const float* qbi  = (const float*)d_in[3];
    const float* Wdw  = (const float*)d_in[4];
    const float* dsc  = (const float*)d_in[5];
    const float* dbi  = (const float*)d_in[6];
    const float* Wp   = (const float*)d_in[7];
    const float* psc  = (const float*)d_in[8];
    const float* pbi  = (const float*)d_in[9];
    const float* ab   = (const float*)d_in[10];
    // d_in[11] = bias_idx: unused (computed analytically)

    float* out = (float*)d_out;
    char*  wsb = (char*)d_ws;
    float* q0   = (float*)wsb;                                  // B*KD*NP f32
    short* kbf  = (short*)(q0 + (size_t)B_ * KD * NP);          // B*NP*16 bf16
    short* vbf  = kbf + (size_t)B_ * NP * 16;                   // B*DV*NP bf16
    float* h    = (float*)(vbf + (size_t)B_ * DV * NP);         // B*C*N3 f32
    float* pacc = h + (size_t)B_ * C_ * N3;                     // B*SPLIT*DV*NP f32
    float* pl   = pacc + (size_t)B_ * SPLIT * DV * NP;          // B*SPLIT*NP f32
    short* whi  = (short*)(pl + (size_t)B_ * SPLIT * NP);       // 256*256 bf16
    short* wlo  = whi + 256 * 256;                              // 256*256 bf16
    short* wqhi = wlo + 256 * 256;                              // 4*96*64 bf16
    short* wqlo = wqhi + NH * QKVO * 64;                        // 4*96*64 bf16

    wprep_kernel<<<256, 256, 0, stream>>>(Wp, whi, wlo, Wqkv, qsc, wqhi, wqlo);

    for (int head = 0; head < NH; head++) {
        qkv_mfma<<<dim3(43, B_), 256, 0, stream>>>(x, h, pacc, pl, wqhi, wqlo, qbi,
                                                   q0, kbf, vbf, head);
        dwconv_kernel<<<dim3(KD, B_), 256, 0, stream>>>(q0, Wdw, dsc, dbi, head);
        attn_partial<<<dim3(43, B_, SPLIT), 256, 0, stream>>>(q0, kbf, vbf, pacc, pl, ab, head);
    }
    proj_kernel<<<dim3(43, B_), 256, 0, stream>>>(h, pacc, pl, whi, wlo, psc, pbi, out);
}

// Round 16
// 314.993 us; speedup vs baseline: 1.0825x; 1.0125x over previous
//
#include <hip/hip_runtime.h>

#define B_    8
#define C_    256
#define R_    14
#define R2    196
#define N3    2744     // 14^3
#define NP    2752     // padded (43*64): guard-free tile staging
#define NH    4
#define KD    16
#define DV    64
#define QKVO  96       // 2*KD + DV
#define MT    64       // m-tile in attention
#define NTILE 43
#define SPLIT 4
#define TPC   11       // tiles per m-chunk

#define SC2   0.36067376f   // 0.25 * log2(e)
#define LOG2E 1.44269504f

typedef __attribute__((ext_vector_type(8))) short short8v;
typedef __attribute__((ext_vector_type(4))) short short4v;
typedef __attribute__((ext_vector_type(4))) float float4v;

__device__ __forceinline__ int iabs(int v){ return v < 0 ? -v : v; }

// fp32 -> bf16 round-to-nearest-even (finite inputs)
__device__ __forceinline__ short f2bf(float f){
    union { float f; unsigned int u; } c; c.f = f;
    return (short)((c.u + 0x7FFFu + ((c.u >> 16) & 1u)) >> 16);
}
__device__ __forceinline__ float bf2f(short s){
    union { unsigned int u; float f; } c; c.u = ((unsigned int)(unsigned short)s) << 16;
    return c.f;
}

// ---------------------------------------------------------------------------
// wprep: Wp -> bf16 hi/lo split; Wqkv*qkv_scale -> bf16 hi/lo split.
// grid 256, block 256 (i < 65536)
// ---------------------------------------------------------------------------
__global__ __launch_bounds__(256)
void wprep_kernel(const float* __restrict__ Wp, short* __restrict__ whi,
                  short* __restrict__ wlo, const float* __restrict__ Wqkv,
                  const float* __restrict__ qsc, short* __restrict__ wqhi,
                  short* __restrict__ wqlo)
{
    int i = blockIdx.x * 256 + threadIdx.x;   // 65536 total
    {
        float w = Wp[i];
        short hi = f2bf(w);
        short lo = f2bf(w - bf2f(hi));
        whi[i] = hi; wlo[i] = lo;
    }
    if (i < NH * QKVO * 64) {                 // 24576
        int o_all = i >> 6;                   // head*96 + o
        float w = Wqkv[i] * qsc[o_all];       // fold scale into W rows
        short hi = f2bf(w);
        short lo = f2bf(w - bf2f(hi));
        wqhi[i] = hi; wqlo[i] = lo;
    }
}

// ---------------------------------------------------------------------------
// QKV: split-bf16 MFMA GEMM + fused combine of PREVIOUS head's partials.
// grid (43, B), block 256
// ---------------------------------------------------------------------------
__global__ __launch_bounds__(256, 2)
void qkv_mfma(const float* __restrict__ x, float* __restrict__ h,
              const float* __restrict__ pacc, const float* __restrict__ pl,
              const short* __restrict__ wqhi, const short* __restrict__ wqlo,
              const float* __restrict__ qbi,
              float* __restrict__ q0, short* __restrict__ kbf, short* __restrict__ vbf,
              int head)
{
    __shared__ short fhi[64][72];   // [n][c] feat hi
    __shared__ short flo[64][72];   // [n][c] feat lo
    __shared__ float bsh[96];
    __shared__ float linv_s[64];

    const int b = blockIdx.y;
    const int n0 = blockIdx.x * 64;
    const int t = threadIdx.x;
    const int w = t >> 6, l = t & 63, g = l >> 4, ln = l & 15;

    if (t < 96) bsh[t] = qbi[head * QKVO + t];

    if (head > 0) {               // stage 1/sum(l) for this n-tile
        if (t < 64) {
            int n = n0 + t;
            float lt = pl[(size_t)(b * SPLIT + 0) * NP + n]
                     + pl[(size_t)(b * SPLIT + 1) * NP + n]
                     + pl[(size_t)(b * SPLIT + 2) * NP + n]
                     + pl[(size_t)(b * SPLIT + 3) * NP + n];
            linv_s[t] = 1.f / lt;  // garbage for pad n (unused)
        }
        __syncthreads();
    }

    // ---- stage feat transposed, hi/lo split: thread = (c = t&63, n-group) ----
    {
        const int sc_ = t & 63;
        const int sng = (t >> 6) * 16;        // n local base
        const int nb = n0 + sng;
        const float* xs = x + ((size_t)b * C_ + head * DV + sc_) * N3 + nb;
        float fv[16];
        const bool fullblk = (nb + 15 < N3);
        if (fullblk) {
#pragma unroll
            for (int e4 = 0; e4 < 4; e4++) {
                float4 xv = ((const float4*)xs)[e4];
                fv[4*e4+0] = xv.x; fv[4*e4+1] = xv.y; fv[4*e4+2] = xv.z; fv[4*e4+3] = xv.w;
            }
        } else {
#pragma unroll
            for (int e = 0; e < 16; e++) fv[e] = (nb + e < N3) ? xs[e] : 0.f;
        }
        if (head > 0) {
            const float* pb = pacc + (size_t)b * SPLIT * DV * NP + (size_t)sc_ * NP + nb;
            float* hw = h + ((size_t)b * C_ + (head - 1) * DV + sc_) * N3 + nb;
            const size_t zs = (size_t)DV * NP;
            if (fullblk) {
#pragma unroll
                for (int e4 = 0; e4 < 4; e4++) {
                    float4 a0 = ((const float4*)(pb         ))[e4];
                    float4 a1 = ((const float4*)(pb +     zs))[e4];
                    float4 a2 = ((const float4*)(pb + 2 * zs))[e4];
                    float4 a3 = ((const float4*)(pb + 3 * zs))[e4];
                    float hc[4];
                    hc[0] = (a0.x + a1.x + a2.x + a3.x) * linv_s[sng + 4*e4 + 0];
                    hc[1] = (a0.y + a1.y + a2.y + a3.y) * linv_s[sng + 4*e4 + 1];
                    hc[2] = (a0.z + a1.z + a2.z + a3.z) * linv_s[sng + 4*e4 + 2];
                    hc[3] = (a0.w + a1.w + a2.w + a3.w) * linv_s[sng + 4*e4 + 3];
                    *(float4*)&hw[4*e4] = make_float4(hc[0], hc[1], hc[2], hc[3]);
                    fv[4*e4+0] += hc[0]; fv[4*e4+1] += hc[1];
                    fv[4*e4+2] += hc[2]; fv[4*e4+3] += hc[3];
                }
            } else {
#pragma unroll
                for (int e = 0; e < 16; e++) {
                    if (nb + e < N3) {
                        float a = pb[e] + pb[e + zs] + pb[e + 2*zs] + pb[e + 3*zs];
                        float hc = a * linv_s[sng + e];
                        hw[e] = hc;
                        fv[e] += hc;
                    }
                }
            }
        }
#pragma unroll
        for (int e = 0; e < 16; e++) {
            short hi = f2bf(fv[e]);
            short lo = f2bf(fv[e] - bf2f(hi));
            fhi[sng + e][sc_] = hi;
            flo[sng + e][sc_] = lo;
        }
    }
    __syncthreads();

    // ---- GEMM: 6 o-subtiles x this wave's n-subtile, K=64 ----
    float4v acc[6];
#pragma unroll
    for (int os = 0; os < 6; os++) acc[os] = (float4v){0.f, 0.f, 0.f, 0.f};

    const short* wqh = wqhi + head * QKVO * 64;
    const short* wql = wqlo + head * QKVO * 64;
#pragma unroll
    for (int ck = 0; ck < 2; ck++) {
        short8v bh = *(const short8v*)&fhi[w * 16 + ln][ck * 32 + g * 8];
        short8v bl = *(const short8v*)&flo[w * 16 + ln][ck * 32 + g * 8];
#pragma unroll
        for (int os = 0; os < 6; os++) {
            size_t off = (size_t)(os * 16 + ln) * 64 + ck * 32 + g * 8;
            short8v wh = *(const short8v*)(wqh + off);
            short8v wl = *(const short8v*)(wql + off);
            acc[os] = __builtin_amdgcn_mfma_f32_16x16x32_bf16(wh, bh, acc[os], 0, 0, 0);
            acc[os] = __builtin_amdgcn_mfma_f32_16x16x32_bf16(wh, bl, acc[os], 0, 0, 0);
            acc[os] = __builtin_amdgcn_mfma_f32_16x16x32_bf16(wl, bh, acc[os], 0, 0, 0);
        }
    }

    // ---- epilogue: D[o = os*16+g*4+r][n = n0+w*16+ln] ----
    const int n_ = n0 + w * 16 + ln;          // < NP always
    const bool ok = n_ < N3;
    float* qo = q0 + (size_t)b * KD * NP;
    short* ko = kbf + (size_t)b * NP * 16 + (size_t)n_ * 16;
    short* vo = vbf + (size_t)b * DV * NP;
#pragma unroll
    for (int os = 0; os < 6; os++) {
#pragma unroll
        for (int r = 0; r < 4; r++) {
            int o = os * 16 + g * 4 + r;
            float y = ok ? acc[os][r] + bsh[o] : 0.f;
            if (o < KD)            qo[(size_t)o * NP + n_] = y;
            else if (o < 2 * KD)   ko[o - KD] = f2bf(y);
            else                   vo[(size_t)(o - 2 * KD) * NP + n_] = f2bf(y);
        }
    }
}

// ---------------------------------------------------------------------------
// Depthwise 5x5x5 SAME conv: zero-padded 18^3 LDS volume, branchless.
// grid (KD, B), block 256
// ---------------------------------------------------------------------------
__global__ __launch_bounds__(256)
void dwconv_kernel(float* __restrict__ q0, const float* __restrict__ Wdw,
                   const float* __restrict__ dsc, const float* __restrict__ dbi,
                   int head)
{
    __shared__ float pv[18 * 18 * 18];
    int b = blockIdx.y, c = blockIdx.x;
    int t = threadIdx.x;
    float* qc = q0 + ((size_t)b * KD + c) * NP;

    for (int i = t; i < 5832; i += 256) pv[i] = 0.f;
    __syncthreads();
    for (int i = t; i < N3; i += 256) {
        int xx = i / R2; int rem = i - xx * R2; int yy = rem / R_; int zz = rem - yy * R_;
        pv[(xx + 2) * 324 + (yy + 2) * 18 + (zz + 2)] = qc[i];
    }
    __syncthreads();

    const float* w = Wdw + (head * KD + c) * 125;
    float scl = dsc[head * KD + c], bia = dbi[head * KD + c];

    if (t < R2) {
        int x = t / R_, y = t - (t / R_) * R_;
        float acc[14];
#pragma unroll
        for (int z = 0; z < 14; z++) acc[z] = 0.f;
#pragma unroll
        for (int a = 0; a < 5; a++) {
#pragma unroll
            for (int bb = 0; bb < 5; bb++) {
                const float* base = &pv[(x + a) * 324 + (y + bb) * 18];
                float col[18];
#pragma unroll
                for (int j = 0; j < 18; j++) col[j] = base[j];
#pragma unroll
                for (int cc = 0; cc < 5; cc++) {
                    float wv = w[a * 25 + bb * 5 + cc];
#pragma unroll
                    for (int z = 0; z < 14; z++) acc[z] += wv * col[z + cc];
                }
            }
        }
        float* qo = qc + x * R2 + y * R_;
#pragma unroll
        for (int z = 0; z < 14; z++) qo[z] = acc[z] * scl + bia;
    }
}

// ---------------------------------------------------------------------------
// Attention partial v16: r15 math (frozen) + occupancy bump:
//   - __launch_bounds__(256, 6): 6 blocks/CU so the 5.4-blocks/CU grid is
//     fully resident (was capped at 4 -> tail round)
//   - patch built directly from global abias (identical values; drops the
//     1.6KB ab2 LDS table -> 23.4KB LDS fits 6 blocks/CU)
// grid (43, B, SPLIT), block 256.
// ---------------------------------------------------------------------------
__global__ __launch_bounds__(256, 6)
void attn_partial(const float* __restrict__ q0, const short* __restrict__ kbf,
                  const short* __restrict__ vbf, float* __restrict__ pacc,
                  float* __restrict__ pl, const float* __restrict__ abias, int head)
{
    __shared__ short ktT[64][40];      // [m][d], d 0..15 real, 16..31 zeros, pad->40
    __shared__ short vtT[64][72];      // [c][m], pad 72
    __shared__ short plds[4][16][72];  // per-wave P [n][m]
    __shared__ int   mja[64];          // per-m mjloc (0..5 real; 6 pad)
    __shared__ float patch[6][8];      // [nj][mj] bias*log2e; unsel = -20000

    const int b = blockIdx.y, z = blockIdx.z;
    const int qbase = blockIdx.x * 64;
    const int t = threadIdx.x;
    const int w = t >> 6;
    const int l = t & 63;
    const int g = l >> 4;
    const int ln = l & 15;

    const float* abh = abias + head * R2;
    const float* qq  = q0  + (size_t)b * KD * NP;
    const short* kbs = kbf + (size_t)b * NP * 16;
    const short* vbs = vbf + (size_t)b * DV * NP;

    // zero-fill ktT d=16..31 (in-loop staging only writes d<16)
    {
        int mm = t & 63, dg = t >> 6;
        short4v zz = {0, 0, 0, 0};
        *(short4v*)&ktT[mm][16 + dg * 4] = zz;
    }

    const int n_my = qbase + w * 16 + ln;
    short8v qf;
#pragma unroll
    for (int j = 0; j < 8; j++) {
        int d = g * 8 + j;
        qf[j] = (d < KD) ? f2bf(qq[(size_t)d * NP + n_my]) : (short)0;
    }
    const int nxy0 = qbase / 14;
    const int njbase = (n_my / 14 - nxy0) * 8;   // per-lane constant, in [0,40]

    float4v acc[4];
#pragma unroll
    for (int cs = 0; cs < 4; cs++) acc[cs] = (float4v){0.f, 0.f, 0.f, 0.f};
    float lsum = 0.f;

    // T14 prefetch registers (staging split: row smm, quarter sq)
    const int smm = t >> 2, sq = t & 3;
    short4v kpre;
    short8v vpre0, vpre1;
    {
        const int m0 = (z * TPC) * MT;
        kpre = *(const short4v*)(kbs + (size_t)(m0 + smm) * 16 + sq * 4);
        const short* vs = vbs + (size_t)smm * NP + m0 + sq * 16;
        vpre0 = ((const short8v*)vs)[0];
        vpre1 = ((const short8v*)vs)[1];
    }

    const int tEnd = min(z * TPC + TPC, NTILE);
    for (int t0 = z * TPC; t0 < tEnd; t0++) {
        const int m0 = t0 * MT;
        __syncthreads();                       // prev tile's LDS reads done
        *(short4v*)&ktT[smm][sq * 4]      = kpre;
        *(short8v*)&vtT[smm][sq * 16]     = vpre0;
        *(short8v*)&vtT[smm][sq * 16 + 8] = vpre1;
        if (t < 64) {                          // per-m mj local index
            int m = m0 + t;
            mja[t] = (m < N3) ? (m / 14 - m0 / 14) : 6;
        } else if (t < 112) {                  // 6x8 bias patch for this tile
            int i = t - 64;
            int nj = i >> 3, mj = i & 7;
            float v = -20000.0f;
            if (mj < 6) {
                int nxy = nxy0 + nj;
                int mxy = m0 / 14 + mj;
                if (nxy < 196 && mxy < 196) {  // else: never selected by real logits
                    int nx = nxy / 14, ny2 = nxy - nx * 14;
                    int mx = mxy / 14, my2 = mxy - mx * 14;
                    int idx = iabs(nx - mx) * 14 + iabs(ny2 - my2);
                    v = abh[idx] * LOG2E;
                }
            }
            patch[nj][mj] = v;
        }
        if (t0 + 1 < tEnd) {                   // prefetch next tile
            const int m1 = (t0 + 1) * MT;
            kpre = *(const short4v*)(kbs + (size_t)(m1 + smm) * 16 + sq * 4);
            const short* vs = vbs + (size_t)smm * NP + m1 + sq * 16;
            vpre0 = ((const short8v*)vs)[0];
            vpre1 = ((const short8v*)vs)[1];
        }
        __syncthreads();                       // tile staged

        const float* pf = &patch[0][0];

        // ---- QK^T + softmax ----
#pragma unroll
        for (int ms = 0; ms < 4; ms++) {
            short8v af = *(const short8v*)&ktT[ms * 16 + ln][g * 8];
            float4v zf = {0.f, 0.f, 0.f, 0.f};
            float4v s = __builtin_amdgcn_mfma_f32_16x16x32_bf16(af, qf, zf, 0, 0, 0);
            int4 pk4 = *(const int4*)&mja[ms * 16 + g * 4];
            int pka[4] = {pk4.x, pk4.y, pk4.z, pk4.w};
            float p[4];
#pragma unroll
            for (int r = 0; r < 4; r++) {
                float bias = pf[njbase + pka[r]];     // broadcast-heavy gather
                float lg2 = fmaf(s[r], SC2, bias);
                p[r] = exp2f(lg2);
                lsum += p[r];
            }
            unsigned pk01, pk23;
            asm("v_cvt_pk_bf16_f32 %0, %1, %2" : "=v"(pk01) : "v"(p[0]), "v"(p[1]));
            asm("v_cvt_pk_bf16_f32 %0, %1, %2" : "=v"(pk23) : "v"(p[2]), "v"(p[3]));
            uint2 pw = make_uint2(pk01, pk23);
            *(uint2*)&plds[w][ln][ms * 16 + g * 4] = pw;
        }

        // ---- PV ----
#pragma unroll
        for (int ck = 0; ck < 2; ck++) {
            short8v pa = *(const short8v*)&plds[w][ln][ck * 32 + g * 8];
#pragma unroll
            for (int cs = 0; cs < 4; cs++) {
                short8v vf = *(const short8v*)&vtT[cs * 16 + ln][ck * 32 + g * 8];
                acc[cs] = __builtin_amdgcn_mfma_f32_16x16x32_bf16(pa, vf, acc[cs], 0, 0, 0);
            }
        }
    }

    // ---- epilogue (proven) ----
    lsum += __shfl_xor(lsum, 16);
    lsum += __shfl_xor(lsum, 32);

    float* pbase = pacc + (size_t)(b * SPLIT + z) * DV * NP;
    if (l < 16) {
        int n_l = qbase + w * 16 + l;
        if (n_l < N3) pl[(size_t)(b * SPLIT + z) * NP + n_l] = lsum;
    }
    const int n0w = qbase + w * 16 + g * 4;
    if (n0w < N3) {
#pragma unroll
        for (int cs = 0; cs < 4; cs++) {
            int c = cs * 16 + ln;
            *(float4v*)&pbase[(size_t)c * NP + n0w] = acc[cs];
        }
    }
}

// ---------------------------------------------------------------------------
// Projection: split-bf16 MFMA + fused combine of head 3 (channels 192..255
// computed inline from pacc/pl — same fp32 sum order as the combine kernel).
// grid (43 n-tiles, B), block 256
// ---------------------------------------------------------------------------
__global__ __launch_bounds__(256, 2)
void proj_kernel(const float* __restrict__ h, const float* __restrict__ pacc,
                 const float* __restrict__ pl, const short* __restrict__ whi,
                 const short* __restrict__ wlo, const float* __restrict__ psc,
                 const float* __restrict__ pbi, float* __restrict__ out)
{
    __shared__ short hhi[64][40];
    __shared__ short hlo[64][40];
    __shared__ float linv_s[64];

    const int b = blockIdx.y;
    const int n0 = blockIdx.x * 64;
    const int t = threadIdx.x;
    const int w = t >> 6, l = t & 63, g = l >> 4, ln = l & 15;

    if (t < 64) {   // 1/sum(l) for head 3 (used by the c0>=192 chunks)
        int n = n0 + t;
        float lt = pl[(size_t)(b * SPLIT + 0) * NP + n]
                 + pl[(size_t)(b * SPLIT + 1) * NP + n]
                 + pl[(size_t)(b * SPLIT + 2) * NP + n]
                 + pl[(size_t)(b * SPLIT + 3) * NP + n];
        linv_s[t] = 1.f / lt;   // garbage for pad n (gated below)
    }

    float4v acc[4][4];
#pragma unroll
    for (int os = 0; os < 4; os++)
#pragma unroll
        for (int ns = 0; ns < 4; ns++) acc[os][ns] = (float4v){0.f, 0.f, 0.f, 0.f};

    const float* hb = h + (size_t)b * C_ * N3;
    const int sc = t >> 3;
    const int sn = (t & 7) * 8;

    for (int c0 = 0; c0 < 256; c0 += 32) {
        __syncthreads();
        if (c0 < 192) {   // heads 0..2: h already materialized
            const float* hsrc = hb + (size_t)(c0 + sc) * N3 + n0 + sn;
            float4 f0 = ((const float4*)hsrc)[0];
            float4 f1 = ((const float4*)hsrc)[1];
            float va[8] = { f0.x, f0.y, f0.z, f0.w, f1.x, f1.y, f1.z, f1.w };
#pragma unroll
            for (int u = 0; u < 8; u++) {
                float v = va[u] > 0.f ? va[u] : 0.f;
                short hi = f2bf(v);
                short lo = f2bf(v - bf2f(hi));
                hhi[sn + u][sc] = hi;
                hlo[sn + u][sc] = lo;
            }
        } else {          // head 3: fused combine from partials
            const int cl = c0 + sc - 192;     // head-3 local channel
            const int nb = n0 + sn;
            const bool in = nb < N3;          // N3 % 8 == 0: per-8 all-in or all-out
            float va[8] = {0,0,0,0,0,0,0,0};
            if (in) {
                const float* pb = pacc + (size_t)b * SPLIT * DV * NP + (size_t)cl * NP + nb;
                const size_t zs = (size_t)DV * NP;
#pragma unroll
                for (int e4 = 0; e4 < 2; e4++) {
                    float4 a0 = ((const float4*)(pb         ))[e4];
                    float4 a1 = ((const float4*)(pb +     zs))[e4];
                    float4 a2 = ((const float4*)(pb + 2 * zs))[e4];
                    float4 a3 = ((const float4*)(pb + 3 * zs))[e4];
                    va[4*e4+0] = (a0.x + a1.x + a2.x + a3.x) * linv_s[sn + 4*e4 + 0];
                    va[4*e4+1] = (a0.y + a1.y + a2.y + a3.y) * linv_s[sn + 4*e4 + 1];
                    va[4*e4+2] = (a0.z + a1.z + a2.z + a3.z) * linv_s[sn + 4*e4 + 2];
                    va[4*e4+3] = (a0.w + a1.w + a2.w + a3.w) * linv_s[sn + 4*e4 + 3];
                }
            }
#pragma unroll
            for (int u = 0; u < 8; u++) {
                float v = va[u] > 0.f ? va[u] : 0.f;
                short hi = f2bf(v);
                short lo = f2bf(v - bf2f(hi));
                hhi[sn + u][sc] = hi;
                hlo[sn + u][sc] = lo;
            }
        }
        __syncthreads();

        short8v wh[4], wl[4];
#pragma unroll
        for (int os = 0; os < 4; os++) {
            size_t off = (size_t)(64 * w + os * 16 + ln) * 256 + c0 + g * 8;
            wh[os] = *(const short8v*)(whi + off);
            wl[os] = *(const short8v*)(wlo + off);
        }
#pragma unroll
        for (int ns = 0; ns < 4; ns++) {
            short8v bh = *(const short8v*)&hhi[ns * 16 + ln][g * 8];
            short8v bl = *(const short8v*)&hlo[ns * 16 + ln][g * 8];
#pragma unroll
            for (int os = 0; os < 4; os++) {
                acc[os][ns] = __builtin_amdgcn_mfma_f32_16x16x32_bf16(wh[os], bh, acc[os][ns], 0, 0, 0);
                acc[os][ns] = __builtin_amdgcn_mfma_f32_16x16x32_bf16(wh[os], bl, acc[os][ns], 0, 0, 0);
                acc[os][ns] = __builtin_amdgcn_mfma_f32_16x16x32_bf16(wl[os], bh, acc[os][ns], 0, 0, 0);
            }
        }
    }

    float* ob = out + (size_t)b * C_ * N3;
#pragma unroll
    for (int os = 0; os < 4; os++) {
#pragma unroll
        for (int r = 0; r < 4; r++) {
            int o = 64 * w + os * 16 + g * 4 + r;
            float s0 = psc[o], b0 = pbi[o];
#pragma unroll
            for (int ns = 0; ns < 4; ns++) {
                int n = n0 + ns * 16 + ln;
                if (n < N3) ob[(size_t)o * N3 + n] = acc[os][ns][r] * s0 + b0;
            }
        }
    }
}

// ---------------------------------------------------------------------------
extern "C" void kernel_launch(void* const* d_in, const int* in_sizes, int n_in,
                              void* d_out, int out_size, void* d_ws, size_t ws_size,
                              hipStream_t stream)
{
    const float* x    = (const float*)d_in[0];
    const float* Wqkv = (const float*)d_in[1];
    const float* qsc  = (const float*)d_in[2];
    const float* qbi  = (const float*)d_in[3];
    const float* Wdw  = (const float*)d_in[4];
    const float* dsc  = (const float*)d_in[5];
    const float* dbi  = (const float*)d_in[6];
    const float* Wp   = (const float*)d_in[7];
    const float* psc  = (const float*)d_in[8];
    const float* pbi  = (const float*)d_in[9];
    const float* ab   = (const float*)d_in[10];
    // d_in[11] = bias_idx: unused (computed analytically)

    float* out = (float*)d_out;
    char*  wsb = (char*)d_ws;
    float* q0   = (float*)wsb;                                  // B*KD*NP f32
    short* kbf  = (short*)(q0 + (size_t)B_ * KD * NP);          // B*NP*16 bf16
    short* vbf  = kbf + (size_t)B_ * NP * 16;                   // B*DV*NP bf16
    float* h    = (float*)(vbf + (size_t)B_ * DV * NP);         // B*C*N3 f32
    float* pacc = h + (size_t)B_ * C_ * N3;                     // B*SPLIT*DV*NP f32
    float* pl   = pacc + (size_t)B_ * SPLIT * DV * NP;          // B*SPLIT*NP f32
    short* whi  = (short*)(pl + (size_t)B_ * SPLIT * NP);       // 256*256 bf16
    short* wlo  = whi + 256 * 256;                              // 256*256 bf16
    short* wqhi = wlo + 256 * 256;                              // 4*96*64 bf16
    short* wqlo = wqhi + NH * QKVO * 64;                        // 4*96*64 bf16

    wprep_kernel<<<256, 256, 0, stream>>>(Wp, whi, wlo, Wqkv, qsc, wqhi, wqlo);

    for (int head = 0; head < NH; head++) {
        qkv_mfma<<<dim3(43, B_), 256, 0, stream>>>(x, h, pacc, pl, wqhi, wqlo, qbi,
                                                   q0, kbf, vbf, head);
        dwconv_kernel<<<dim3(KD, B_), 256, 0, stream>>>(q0, Wdw, dsc, dbi, head);
        attn_partial<<<dim3(43, B_, SPLIT), 256, 0, stream>>>(q0, kbf, vbf, pacc, pl, ab, head);
    }
    proj_kernel<<<dim3(43, B_), 256, 0, stream>>>(h, pacc, pl, whi, wlo, psc, pbi, out);
}